// Round 1
// 293.327 us; speedup vs baseline: 1.0170x; 1.0170x over previous
//
#include <hip/hip_runtime.h>
#include <hip/hip_bf16.h>

// Inputs/outputs are FLOAT32 (reference dtype). bf16 used only internally for MFMA.
typedef __bf16 bf16_t;
typedef bf16_t bf16x8 __attribute__((ext_vector_type(8)));
typedef bf16_t bf16x4 __attribute__((ext_vector_type(4)));
typedef float  f32x4  __attribute__((ext_vector_type(4)));

#define MFMA(a,b,c) __builtin_amdgcn_mfma_f32_16x16x32_bf16((a),(b),(c),0,0,0)

// ---------------- small graph chain ----------------

// M = final_w[:, :256] @ gw_w  (stored bf16). Block 0 also zeroes accumulators.
__global__ __launch_bounds__(256) void k_M(const float* final_w, const float* gw_w,
                                           bf16_t* M16, float* xsum, float* fmaxb,
                                           float* cmaxb) {
  int o = blockIdx.x, c = threadIdx.x;
  __shared__ float fw[256];
  fw[c] = final_w[o*512 + c];
  __syncthreads();
  float acc = 0.f;
  for (int k = 0; k < 256; ++k) acc += fw[k] * gw_w[k*256 + c];
  M16[o*256 + c] = (bf16_t)acc;
  if (o == 0) {
    for (int i = c; i < 4096; i += 256) xsum[i] = 0.f;
    fmaxb[c] = 0.f;
    if (c < 16) cmaxb[c] = 0.f;
  }
}

// q,k,v = emb @ {wq,wk,wv} + bias   grid 3*20, block 320
__global__ __launch_bounds__(320) void k_qkv(const float* emb,
    const float* wq, const float* bq, const float* wk, const float* bk,
    const float* wv, const float* bv, float* qkv) {
  int mat = blockIdx.x / 20, row = blockIdx.x % 20, t = threadIdx.x;
  const float* W = mat == 0 ? wq : (mat == 1 ? wk : wv);
  const float* Bv = mat == 0 ? bq : (mat == 1 ? bk : bv);
  __shared__ float er[300];
  if (t < 300) er[t] = emb[row*300 + t];
  __syncthreads();
  if (t < 300) {
    float acc = Bv[t];
    for (int d = 0; d < 300; ++d) acc += er[d] * W[d*300 + t];
    qkv[(mat*20 + row)*300 + t] = acc;
  }
}

// attention on emb graph -> ev ; also adj_n.  1 block, 512 threads
__global__ __launch_bounds__(512) void k_attn(const float* emb, const float* wo, const float* bo,
                                              const float* adj, const float* qkv,
                                              float* ev, float* adjn) {
  __shared__ float qs[6000], ks[6000];
  __shared__ float att[400], wsum[20], n1[300], n2[300], drt[20];
  int t = threadIdx.x;
  for (int i = t; i < 6000; i += 512) { qs[i] = qkv[i]; ks[i] = qkv[6000 + i]; }
  if (t >= 480 && t < 500) {
    int i = t - 480; float s = 1.f;
    for (int j = 0; j < 20; ++j) s += adj[i*20 + j];
    drt[i] = rsqrtf(s);
  }
  __syncthreads();
  if (t < 400) {
    int i = t / 20, j = t % 20;
    float acc = 0.f;
    for (int d = 0; d < 300; ++d) acc += qs[i*300 + d] * ks[j*300 + d];
    att[t] = acc * 0.05773502691896258f;  // 1/sqrt(300)
  }
  __syncthreads();
  if (t < 20) {
    float m = -1e30f;
    for (int j = 0; j < 20; ++j) m = fmaxf(m, att[t*20 + j]);
    float s = 0.f;
    for (int j = 0; j < 20; ++j) { float e = __expf(att[t*20 + j] - m); att[t*20 + j] = e; s += e; }
    float inv = 1.f / s;
    for (int j = 0; j < 20; ++j) att[t*20 + j] *= inv;
  }
  __syncthreads();
  if (t < 20) {  // wsum[j] = mean over i of att[i][j]
    float s = 0.f;
    for (int i = 0; i < 20; ++i) s += att[i*20 + t];
    wsum[t] = s * 0.05f;
  }
  __syncthreads();
  if (t < 300) {
    const float* v = qkv + 12000;
    float acc = 0.f;
    for (int j = 0; j < 20; ++j) acc += wsum[j] * v[j*300 + t];
    n1[t] = acc;
  }
  __syncthreads();
  if (t < 300) {
    float acc = bo[t];
    for (int d = 0; d < 300; ++d) acc += n1[d] * wo[d*300 + t];
    n2[t] = acc;
  }
  __syncthreads();
  for (int i = t; i < 6000; i += 512) ev[i] = emb[i] + n2[i % 300];
  if (t < 400) {
    int i = t / 20, j = t % 20;
    float a = adj[t] + (i == j ? 1.f : 0.f);
    adjn[t] = drt[i] * a * drt[j];
  }
}

// h1 = ev @ gc1_w   grid 20, block 256
__global__ __launch_bounds__(256) void k_h1(const float* ev, const float* gc1_w, float* h1) {
  int n = blockIdx.x, c = threadIdx.x;
  __shared__ float er[300];
  for (int i = c; i < 300; i += 256) er[i] = ev[n*300 + i];
  __syncthreads();
  float acc = 0.f;
  for (int d = 0; d < 300; ++d) acc += er[d] * gc1_w[d*256 + c];
  h1[n*256 + c] = acc;
}

// g1 = relu(adjn @ h1) ; h2 = g1 @ gc2_w   grid 20, block 256
__global__ __launch_bounds__(256) void k_g1h2(const float* adjn, const float* h1,
                                              const float* gc2_w, float* h2) {
  int n = blockIdx.x, c = threadIdx.x;
  __shared__ float ar[20], g1r[256];
  if (c < 20) ar[c] = adjn[n*20 + c];
  __syncthreads();
  float acc = 0.f;
  for (int m = 0; m < 20; ++m) acc += ar[m] * h1[m*256 + c];
  g1r[c] = fmaxf(acc, 0.f);
  __syncthreads();
  float h = 0.f;
  for (int d = 0; d < 256; ++d) h += g1r[d] * gc2_w[d*256 + c];
  h2[n*256 + c] = h;
}

// g2 = relu(adjn @ h2); rg = sum_n g2; u = fw2 @ rg.  1 block 256
__global__ __launch_bounds__(256) void k_g2u(const float* adjn, const float* h2,
                                             const float* final_w, float* u) {
  int c = threadIdx.x;
  __shared__ float an[400], rg[256];
  for (int i = c; i < 400; i += 256) an[i] = adjn[i];
  __syncthreads();
  float gs = 0.f;
  for (int n = 0; n < 20; ++n) {
    float acc = 0.f;
    for (int m = 0; m < 20; ++m) acc += an[n*20 + m] * h2[m*256 + c];
    gs += fmaxf(acc, 0.f);
  }
  rg[c] = gs;
  __syncthreads();
  float acc = 0.f;
  for (int k = 0; k < 256; ++k) acc += final_w[c*512 + 256 + k] * rg[k];
  u[c] = acc;
}

// ---------------- big path ----------------

// phi -> fB=relu(phi+b) bf16, fmax per (b,m), csum[b,q]=col sums + cmax, s_raw, xsum.
// grid (9, 16): role 0..7 -> phi/s/csum for 128 hw; role 8 -> xsum.
__global__ __launch_bounds__(256) void k_phis(const float* x, const float* phi_w,
    const float* phi_b, const float* s2l_w,
    bf16_t* fB, float* fmaxb, float* s_raw, float* xsum, float* csum, float* cmaxb) {
  int b = blockIdx.y, role = blockIdx.x, t = threadIdx.x;
  const float* xb = x + b*262144;
  if (role == 8) {
    int wv = t >> 6, lane = t & 63;
    for (int c = wv; c < 256; c += 4) {
      float acc = 0.f;
      const float* p = xb + c*1024 + lane;
      #pragma unroll
      for (int k = 0; k < 16; ++k) acc += p[k*64];
      #pragma unroll
      for (int off = 32; off; off >>= 1) acc += __shfl_down(acc, off, 64);
      if (lane == 0) atomicAdd(&xsum[b*256 + c], acc);
    }
    return;
  }
  __shared__ float pw[4096], wi[256], pb[16];
  __shared__ float phs[128][18];
  __shared__ unsigned fmu[16];
  __shared__ unsigned cmu;
  for (int i = t; i < 4096; i += 256) pw[i] = phi_w[i];
  wi[t] = s2l_w[t];
  if (t < 16) { pb[t] = phi_b[t]; fmu[t] = 0u; }
  if (t == 0) cmu = 0u;
  __syncthreads();
  int hwl = t & 127, half = t >> 7;
  int hw = role*128 + hwl;
  float ph[16];
  #pragma unroll
  for (int o = 0; o < 16; ++o) ph[o] = 0.f;
  float sacc = 0.f;
  for (int ci = 0; ci < 128; ++ci) {
    int c = half*128 + ci;
    float xv = xb[c*1024 + hw];
    sacc += wi[c] * xv;
    #pragma unroll
    for (int o = 0; o < 16; ++o) ph[o] += pw[o*256 + c] * xv;
  }
  if (half == 0) {
    #pragma unroll
    for (int o = 0; o < 16; ++o) phs[hwl][o] = ph[o];
    phs[hwl][16] = sacc;
  }
  __syncthreads();
  if (half == 1) {
    #pragma unroll
    for (int o = 0; o < 16; ++o) phs[hwl][o] += ph[o];
    s_raw[b*1024 + hw] = phs[hwl][16] + sacc;
  }
  __syncthreads();
  float csacc = 0.f;
  #pragma unroll
  for (int i = 0; i < 8; ++i) {
    int j = i*256 + t;
    int o = j >> 7, hl = j & 127;     // hl == t&127; o covers 8 values per thread
    float val = fmaxf(phs[hl][o] + pb[o], 0.f);
    bf16_t bv = (bf16_t)val;
    atomicMax(&fmu[o], __float_as_uint((float)bv));
    fB[b*16384 + o*1024 + role*128 + hl] = bv;
    csacc += (float)bv;
  }
  if (half == 0) phs[hwl][17] = csacc;
  __syncthreads();                       // fmu complete; csacc halves staged
  if (half == 1) {
    float cs = phs[hwl][17] + csacc;     // full c[q] = sum_m fB[b,m,q]
    csum[b*1024 + hw] = cs;
    atomicMax(&cmu, __float_as_uint(cs));  // cs >= 0
  }
  if (t < 16) atomicMax((unsigned*)&fmaxb[b*16 + t], fmu[t]);
  __syncthreads();
  if (t == 0) atomicMax((unsigned*)&cmaxb[b], cmu);
}

// dgd = sigmoid(g) - 0.5 = 0.5*tanh(g/2); mcol = softmax_p(s_raw).  grid 16
__global__ __launch_bounds__(256) void k_dgm(const float* xsum, const float* glob_w,
    const float* s_raw, float* dgd, float* mcol) {
  int b = blockIdx.x, t = threadIdx.x;
  __shared__ float xm[256], red[8];
  xm[t] = xsum[b*256 + t] * (1.f / 1024.f);
  __syncthreads();
  if (t < 16) {
    float g = 0.f;
    for (int c = 0; c < 256; ++c) g += glob_w[t*256 + c] * xm[c];
    dgd[b*16 + t] = 0.5f * tanhf(0.5f * g);   // sigmoid(g) - 0.5
  }
  // mcol softmax over 1024
  float v[4]; float m = -1e30f;
  #pragma unroll
  for (int i = 0; i < 4; ++i) { v[i] = s_raw[b*1024 + t + i*256]; m = fmaxf(m, v[i]); }
  #pragma unroll
  for (int off = 32; off; off >>= 1) m = fmaxf(m, __shfl_xor(m, off, 64));
  if ((t & 63) == 0) red[t >> 6] = m;
  __syncthreads();
  float bm = fmaxf(fmaxf(red[0], red[1]), fmaxf(red[2], red[3]));
  float e[4]; float sum = 0.f;
  #pragma unroll
  for (int i = 0; i < 4; ++i) { e[i] = __expf(v[i] - bm); sum += e[i]; }
  #pragma unroll
  for (int off = 32; off; off >>= 1) sum += __shfl_xor(sum, off, 64);
  if ((t & 63) == 0) red[4 + (t >> 6)] = sum;
  __syncthreads();
  float inv = 1.f / (red[4] + red[5] + red[6] + red[7]);
  #pragma unroll
  for (int i = 0; i < 4; ++i) mcol[b*1024 + t + i*256] = e[i] * inv;
}

// Fused main. S[p,q] = sum_m e'[p,m] f[m,q]  (MFMA, K 16->32 pad)  + 0.5*a[p]*c[q] (fp32).
// Single pass over q: E=exp(S-Mb), rowsum rs and S2u[p,c] += E @ x_r; then
// T = x_r - S2u/rs in LDS; GEMM2 out = relu(M @ T^T + mcol*u + x).
// p-tile = 32 rows.  grid (32 p-tiles, 16 b) = 512 blocks -> 2 blocks/CU.
// XCD-aware remap: each XCD's blocks cover exactly 2 batches (2MB x in 4MB L2).
__global__ __launch_bounds__(256) void k_main(const float* x, const bf16_t* fB,
    const bf16_t* M16, const float* fmaxb, const float* mcol, const float* u,
    const float* dgd, const float* csum, const float* cmaxb, float* out) {
  int flat = blockIdx.y * 32 + blockIdx.x;
  int b  = (flat & 7) * 2 + ((flat >> 3) >> 5);   // bijective: flat = (b>>1) + 8*((b&1)*32 + pt)
  int p0 = ((flat >> 3) & 31) * 32;
  int t = threadIdx.x, w = t >> 6, l = t & 63, lr = l & 15, quad = l >> 4;
  int qh = w >> 1, ph = w & 1;                     // wave's q-half / p-half in the S step
  __shared__ __align__(16) char smem[16896];       // union: phase1 | T_ls
  bf16_t* e_s = (bf16_t*)smem;                     // [32][40] e' (m>=16 zero)
  bf16_t* fT  = (bf16_t*)(smem + 2560);            // [32][40] f tile (m>=16 zero)
  bf16_t* PT  = (bf16_t*)(smem + 5120);            // [32][40] E tiles [p][q]
  bf16_t* T_ls = (bf16_t*)smem;                    // [32][264] phase 2
  __shared__ float Mb_s[32], fmax_s[16], u_s[256], rsinv_s[32], dgd_s[16];
  __shared__ float c_s[1024], ha_s[32], rs_s[2][32];
  const float*  xb  = x  + b*262144;
  const bf16_t* fBb = fB + b*16384;
  for (int i = t; i < 1280; i += 256) { e_s[i] = (bf16_t)0.f; fT[i] = (bf16_t)0.f; }
  u_s[t] = u[t];
  for (int i = t; i < 1024; i += 256) c_s[i] = csum[b*1024 + i];
  if (t < 16) { fmax_s[t] = fmaxb[b*16 + t]; dgd_s[t] = dgd[b*16 + t]; }
  __syncthreads();
  for (int i = t; i < 512; i += 256) {       // e'[p,m] = x_phi * (sig(g[m])-0.5)
    int p = i >> 4, m = i & 15;
    e_s[p*40 + m] = (bf16_t)((float)fBb[p0*16 + i] * dgd_s[m]);
  }
  __syncthreads();
  if (t < 32) {
    float a = 0.f;
    #pragma unroll
    for (int m = 0; m < 16; ++m) a += (float)fBb[(p0 + t)*16 + m];
    float ha = 0.5f * a;
    ha_s[t] = ha;
    float mb = ha * cmaxb[b];
    #pragma unroll
    for (int m = 0; m < 16; ++m) mb += fmaxf((float)e_s[t*40 + m], 0.f) * fmax_s[m];
    Mb_s[t] = mb;  // exact upper bound on row max of S
  }
  __syncthreads();
  bf16x8 be = *(const bf16x8*)(e_s + (ph*16 + lr)*40 + quad*8);  // p = ph*16+lr
  float mb_lane = Mb_s[ph*16 + lr];
  float ha_lane = ha_s[ph*16 + lr];
  float rs = 0.f;
  f32x4 acc[2][4];  // S2u[p = pf*16+quad*4+r][c = w*64+cf*16+lr]
  #pragma unroll
  for (int i = 0; i < 2; ++i)
    #pragma unroll
    for (int j = 0; j < 4; ++j) acc[i][j] = (f32x4){0.f, 0.f, 0.f, 0.f};
  for (int st = 0; st < 32; ++st) {
    int e0 = t, e1 = t + 256;  // 512 elems: m = e>>5, qi = e&31
    fT[(e0 & 31)*40 + (e0 >> 5)] = fBb[(e0 >> 5)*1024 + st*32 + (e0 & 31)];
    fT[(e1 & 31)*40 + (e1 >> 5)] = fBb[(e1 >> 5)*1024 + st*32 + (e1 & 31)];
    __syncthreads();
    // wave (qh,ph): S quarter D[q=qh*16+quad*4+r][p=ph*16+lr]
    bf16x8 a0 = *(const bf16x8*)(fT + (qh*16 + lr)*40 + quad*8);
    f32x4 z = {0.f, 0.f, 0.f, 0.f};
    f32x4 s0 = MFMA(a0, be, z);
    bf16x4 pv;
    #pragma unroll
    for (int r = 0; r < 4; ++r) {
      float S0 = s0[r] + ha_lane * c_s[st*32 + qh*16 + quad*4 + r];
      float E0 = __expf(S0 - mb_lane);
      rs += E0;
      pv[r] = (bf16_t)E0;
    }
    *(bf16x4*)(PT + (ph*16 + lr)*40 + qh*16 + quad*4) = pv;
    __syncthreads();
    bf16x8 ap[2];
    ap[0] = *(const bf16x8*)(PT + lr*40 + quad*8);
    ap[1] = *(const bf16x8*)(PT + (16 + lr)*40 + quad*8);
    #pragma unroll
    for (int cf = 0; cf < 4; ++cf) {
      bf16x8 bv;
      const float* xp = xb + (st*32 + quad*8)*256 + w*64 + cf*16 + lr;
      #pragma unroll
      for (int j = 0; j < 8; ++j) bv[j] = (bf16_t)xp[j*256];   // x_r[q][c] raw reshape
      acc[0][cf] = MFMA(ap[0], bv, acc[0][cf]);
      acc[1][cf] = MFMA(ap[1], bv, acc[1][cf]);
    }
  }
  rs += __shfl_xor(rs, 16, 64);
  rs += __shfl_xor(rs, 32, 64);          // sum over quads: qh-half rowsum for p = ph*16+lr
  if (l < 16) rs_s[qh][ph*16 + lr] = rs;
  __syncthreads();   // rs halves staged; all PT/fT/e_s reads drained -> T_ls may overwrite
  if (t < 32) rsinv_s[t] = 1.f / fmaxf(rs_s[0][t] + rs_s[1][t], 1e-30f);
  __syncthreads();
  #pragma unroll
  for (int pf = 0; pf < 2; ++pf)
    #pragma unroll
    for (int cf = 0; cf < 4; ++cf)
      #pragma unroll
      for (int r = 0; r < 4; ++r) {
        int p = pf*16 + quad*4 + r;
        int c = w*64 + cf*16 + lr;
        float tv = xb[(p0 + p)*256 + c] - acc[pf][cf][r] * rsinv_s[p];
        T_ls[p*264 + c] = (bf16_t)tv;    // spiral[p][c]
      }
  __syncthreads();
  f32x4 acc2[4][2];  // D2[o = w*64+of*16+quad*4+r][p = pf*16+lr]
  #pragma unroll
  for (int i = 0; i < 4; ++i)
    #pragma unroll
    for (int j = 0; j < 2; ++j) acc2[i][j] = (f32x4){0.f, 0.f, 0.f, 0.f};
  for (int c0 = 0; c0 < 256; c0 += 32) {
    bf16x8 am[4], bt[2];
    #pragma unroll
    for (int of = 0; of < 4; ++of)
      am[of] = *(const bf16x8*)(M16 + (w*64 + of*16 + lr)*256 + c0 + quad*8);
    #pragma unroll
    for (int pf = 0; pf < 2; ++pf)
      bt[pf] = *(const bf16x8*)(T_ls + (pf*16 + lr)*264 + c0 + quad*8);
    #pragma unroll
    for (int of = 0; of < 4; ++of)
      #pragma unroll
      for (int pf = 0; pf < 2; ++pf) acc2[of][pf] = MFMA(am[of], bt[pf], acc2[of][pf]);
  }
  float* outb = out + b*262144;
  #pragma unroll
  for (int of = 0; of < 4; ++of)
    #pragma unroll
    for (int pf = 0; pf < 2; ++pf)
      #pragma unroll
      for (int r = 0; r < 4; ++r) {
        int o = w*64 + of*16 + quad*4 + r;
        int pg = p0 + pf*16 + lr;
        float v = acc2[of][pf][r] + mcol[b*1024 + pg] * u_s[o] + xb[o*1024 + pg];
        outb[o*1024 + pg] = fmaxf(v, 0.f);
      }
}

// ---------------- launch ----------------

extern "C" void kernel_launch(void* const* d_in, const int* in_sizes, int n_in,
                              void* d_out, int out_size, void* d_ws, size_t ws_size,
                              hipStream_t stream) {
  (void)in_sizes; (void)n_in; (void)out_size; (void)ws_size;
  const float* x       = (const float*)d_in[0];
  const float* emb     = (const float*)d_in[1];
  const float* adj     = (const float*)d_in[2];
  const float* wq      = (const float*)d_in[3];
  const float* bq      = (const float*)d_in[4];
  const float* wk      = (const float*)d_in[5];
  const float* bk      = (const float*)d_in[6];
  const float* wv      = (const float*)d_in[7];
  const float* bv      = (const float*)d_in[8];
  const float* wo      = (const float*)d_in[9];
  const float* bo      = (const float*)d_in[10];
  const float* phi_w   = (const float*)d_in[11];
  const float* phi_b   = (const float*)d_in[12];
  const float* glob_w  = (const float*)d_in[13];
  const float* gc1_w   = (const float*)d_in[14];
  const float* gc2_w   = (const float*)d_in[15];
  const float* gw_w    = (const float*)d_in[16];
  const float* s2l_w   = (const float*)d_in[17];
  const float* final_w = (const float*)d_in[19];
  float* out = (float*)d_out;

  float* W = (float*)d_ws;
  float* qkv   = W + 0;        // 18000
  float* ev    = W + 18048;    // 6000
  float* adjn  = W + 24064;    // 400
  float* h1    = W + 24512;    // 5120
  float* h2    = W + 29632;    // 5120
  float* u     = W + 34752;    // 256
  float* xsum  = W + 35008;    // 4096
  float* s_raw = W + 39360;    // 16384
  float* mcol  = W + 55744;    // 16384
  float* fmaxb = W + 72128;    // 256
  float* dgd   = W + 72384;    // 256
  float* csum  = W + 72640;    // 16384
  float* cmaxb = W + 89024;    // 16
  bf16_t* M16 = (bf16_t*)((char*)d_ws + 356352);           // 65536 bf16 (128 KB)
  bf16_t* fB  = (bf16_t*)((char*)d_ws + 356352 + 131072);  // 262144 bf16 (512 KB)
  // total ws usage ~0.97 MB

  k_M    <<<256, 256, 0, stream>>>(final_w, gw_w, M16, xsum, fmaxb, cmaxb);
  k_qkv  <<<60, 320, 0, stream>>>(emb, wq, bq, wk, bk, wv, bv, qkv);
  k_attn <<<1, 512, 0, stream>>>(emb, wo, bo, adj, qkv, ev, adjn);
  k_h1   <<<20, 256, 0, stream>>>(ev, gc1_w, h1);
  k_g1h2 <<<20, 256, 0, stream>>>(adjn, h1, gc2_w, h2);
  k_g2u  <<<1, 256, 0, stream>>>(adjn, h2, final_w, u);
  k_phis <<<dim3(9, 16), 256, 0, stream>>>(x, phi_w, phi_b, s2l_w, fB, fmaxb, s_raw, xsum, csum, cmaxb);
  k_dgm  <<<16, 256, 0, stream>>>(xsum, glob_w, s_raw, dgd, mcol);
  k_main <<<dim3(32, 16), 256, 0, stream>>>(x, fB, M16, fmaxb, mcol, u, dgd, csum, cmaxb, out);
}

// Round 2
// 281.614 us; speedup vs baseline: 1.0593x; 1.0416x over previous
//
#include <hip/hip_runtime.h>
#include <hip/hip_bf16.h>

// Inputs/outputs are FLOAT32 (reference dtype). bf16 used only internally for MFMA.
typedef __bf16 bf16_t;
typedef bf16_t bf16x8 __attribute__((ext_vector_type(8)));
typedef bf16_t bf16x4 __attribute__((ext_vector_type(4)));
typedef float  f32x4  __attribute__((ext_vector_type(4)));

#define MFMA(a,b,c) __builtin_amdgcn_mfma_f32_16x16x32_bf16((a),(b),(c),0,0,0)

// =================== LAUNCH A: k_front ===================
// roles by blockIdx.x:
//   [0,256)      : M = final_w[:, :256] @ gw_w  (bf16)
//   [256,316)    : qkv = emb @ {wq,wk,wv} + bias
//   [316,460)    : phis (9 roles x 16 b): fB, fBT, s_raw, csum, fmax/cmax partials, xsum
//   [460,1484)   : xT transpose: x raw [1024q][256c] fp32 -> xT [256c][1024q] bf16
__global__ __launch_bounds__(256) void k_front(
    const float* final_w, const float* gw_w, const float* emb,
    const float* wq, const float* bq, const float* wk, const float* bk,
    const float* wv, const float* bvv, const float* x,
    const float* phi_w, const float* phi_b, const float* s2l_w,
    bf16_t* M16, float* qkv, bf16_t* fB, bf16_t* fBT, float* s_raw,
    float* xsum, float* csum, float* fmaxp, float* cmaxp, bf16_t* xT) {
  __shared__ __align__(16) char sp[27648];
  int bid = blockIdx.x, t = threadIdx.x;
  if (bid < 256) {                       // ---- k_M ----
    float* fw = (float*)sp;
    int o = bid, c = t;
    fw[c] = final_w[o*512 + c];
    __syncthreads();
    float acc = 0.f;
    for (int k = 0; k < 256; ++k) acc += fw[k] * gw_w[k*256 + c];
    M16[o*256 + c] = (bf16_t)acc;
    return;
  }
  if (bid < 316) {                       // ---- k_qkv ----
    int id = bid - 256;
    int mat = id / 20, row = id % 20;
    const float* W  = mat == 0 ? wq : (mat == 1 ? wk : wv);
    const float* Bb = mat == 0 ? bq : (mat == 1 ? bk : bvv);
    float* er = (float*)sp;
    for (int i = t; i < 300; i += 256) er[i] = emb[row*300 + i];
    __syncthreads();
    for (int o = t; o < 300; o += 256) {
      float acc = Bb[o];
      for (int d = 0; d < 300; ++d) acc += er[d] * W[d*300 + o];
      qkv[(mat*20 + row)*300 + o] = acc;
    }
    return;
  }
  if (bid < 460) {                       // ---- k_phis ----
    int id = bid - 316;
    int b = id / 9, role = id % 9;
    const float* xb = x + b*262144;
    if (role == 8) {
      int wv2 = t >> 6, lane = t & 63;
      for (int c = wv2; c < 256; c += 4) {
        float acc = 0.f;
        const float* p = xb + c*1024 + lane;
        #pragma unroll
        for (int k = 0; k < 16; ++k) acc += p[k*64];
        #pragma unroll
        for (int off = 32; off; off >>= 1) acc += __shfl_down(acc, off, 64);
        if (lane == 0) xsum[b*256 + c] = acc;
      }
      return;
    }
    float* pw = (float*)sp;              // 4096
    float* wi = pw + 4096;               // 256
    float* pb = wi + 256;                // 16
    float* phs = pb + 16;                // [128][18]
    unsigned* fmu = (unsigned*)(phs + 2304);  // 16
    unsigned* cmu = fmu + 16;            // 1
    for (int i = t; i < 4096; i += 256) pw[i] = phi_w[i];
    wi[t] = s2l_w[t];
    if (t < 16) { pb[t] = phi_b[t]; fmu[t] = 0u; }
    if (t == 0) cmu[0] = 0u;
    __syncthreads();
    int hwl = t & 127, half = t >> 7;
    int hw = role*128 + hwl;
    float ph[16];
    #pragma unroll
    for (int o = 0; o < 16; ++o) ph[o] = 0.f;
    float sacc = 0.f;
    for (int ci = 0; ci < 128; ++ci) {
      int c = half*128 + ci;
      float xv = xb[c*1024 + hw];
      sacc += wi[c] * xv;
      #pragma unroll
      for (int o = 0; o < 16; ++o) ph[o] += pw[o*256 + c] * xv;
    }
    if (half == 0) {
      #pragma unroll
      for (int o = 0; o < 16; ++o) phs[hwl*18 + o] = ph[o];
      phs[hwl*18 + 16] = sacc;
    }
    __syncthreads();
    if (half == 1) {
      #pragma unroll
      for (int o = 0; o < 16; ++o) phs[hwl*18 + o] += ph[o];
      s_raw[b*1024 + hw] = phs[hwl*18 + 16] + sacc;
    }
    __syncthreads();
    float csacc = 0.f;
    #pragma unroll
    for (int i = 0; i < 8; ++i) {
      int j = i*256 + t;
      int o = j >> 7, hl = j & 127;
      float val = fmaxf(phs[hl*18 + o] + pb[o], 0.f);
      bf16_t bv16 = (bf16_t)val;
      atomicMax(&fmu[o], __float_as_uint((float)bv16));
      fB [b*16384 + o*1024 + role*128 + hl] = bv16;            // m-major (raw)
      fBT[b*16384 + (role*128 + hl)*16 + o] = bv16;            // q-major
      csacc += (float)bv16;
    }
    if (half == 0) phs[hwl*18 + 17] = csacc;
    __syncthreads();
    if (half == 1) {
      float cs = phs[hwl*18 + 17] + csacc;
      csum[b*1024 + hw] = cs;
      atomicMax(cmu, __float_as_uint(cs));
    }
    if (t < 16) fmaxp[b*128 + role*16 + t] = __uint_as_float(fmu[t]);
    __syncthreads();
    if (t == 0) cmaxp[b*8 + role] = __uint_as_float(cmu[0]);
    return;
  }
  {                                      // ---- k_xt ----
    int id = bid - 460;                  // 0..1023
    int bb = id >> 6, tile = id & 63;
    int q0 = (tile >> 2) * 64, c0 = (tile & 3) * 64;
    bf16_t* tl = (bf16_t*)sp;            // [64][74]
    const float* xbb = x + bb*262144;
    #pragma unroll
    for (int k = 0; k < 16; ++k) {
      int idx = k*256 + t, qi = idx >> 6, ci = idx & 63;
      tl[ci*74 + qi] = (bf16_t)xbb[(q0 + qi)*256 + c0 + ci];
    }
    __syncthreads();
    #pragma unroll
    for (int k = 0; k < 16; ++k) {
      int idx = k*256 + t, ci = idx >> 6, qi = idx & 63;
      xT[bb*262144 + (c0 + ci)*1024 + q0 + qi] = tl[ci*74 + qi];
    }
    return;
  }
}

// =================== LAUNCH B: k_mid (512 threads) ===================
// block 0   : attn + ev + adjn + h1 + g1 + h2 + g2/rg + u, all in LDS
// blocks 1-16: dgm for b = blockIdx.x-1, plus fmax/cmax partial reduction
__global__ __launch_bounds__(512) void k_mid(
    const float* emb, const float* adj, const float* wo, const float* bo,
    const float* qkv, const float* gc1_w, const float* gc2_w, const float* final_w,
    const float* glob_w, const float* xsum, const float* s_raw,
    const float* fmaxp, const float* cmaxp,
    float* u, float* dgd, float* mcol, float* fmaxb, float* cmaxb) {
  __shared__ __align__(16) float sp[14216];
  int t = threadIdx.x;
  if (blockIdx.x == 0) {
    float* A  = sp;            // 6000: q -> ev -> g1
    float* Bs = A + 6000;      // 6000: k -> h1 -> h2
    float* att  = Bs + 6000;   // 400
    float* wsum = att + 400;   // 20
    float* n1   = wsum + 20;   // 304
    float* n2   = n1 + 304;    // 304
    float* drt  = n2 + 304;    // 20
    float* an   = drt + 20;    // 400
    float* rg   = an + 400;    // 256
    float* rg2  = rg + 256;    // 512
    for (int i = t; i < 6000; i += 512) { A[i] = qkv[i]; Bs[i] = qkv[6000 + i]; }
    if (t >= 480 && t < 500) {
      int i = t - 480; float s = 1.f;
      for (int j = 0; j < 20; ++j) s += adj[i*20 + j];
      drt[i] = rsqrtf(s);
    }
    __syncthreads();
    if (t < 400) {
      int i = t / 20, j = t % 20;
      float acc = 0.f;
      for (int d = 0; d < 300; ++d) acc += A[i*300 + d] * Bs[j*300 + d];
      att[t] = acc * 0.05773502691896258f;  // 1/sqrt(300)
    }
    __syncthreads();
    if (t < 20) {
      float m = -1e30f;
      for (int j = 0; j < 20; ++j) m = fmaxf(m, att[t*20 + j]);
      float s = 0.f;
      for (int j = 0; j < 20; ++j) { float e = __expf(att[t*20 + j] - m); att[t*20 + j] = e; s += e; }
      float inv = 1.f / s;
      for (int j = 0; j < 20; ++j) att[t*20 + j] *= inv;
    }
    __syncthreads();
    if (t < 20) {
      float s = 0.f;
      for (int i = 0; i < 20; ++i) s += att[i*20 + t];
      wsum[t] = s * 0.05f;
    }
    __syncthreads();
    if (t < 300) {
      const float* v = qkv + 12000;
      float acc = 0.f;
      for (int j = 0; j < 20; ++j) acc += wsum[j] * v[j*300 + t];
      n1[t] = acc;
    }
    __syncthreads();
    if (t < 300) {
      float acc = bo[t];
      for (int d = 0; d < 300; ++d) acc += n1[d] * wo[d*300 + t];
      n2[t] = acc;
    }
    __syncthreads();
    for (int i = t; i < 6000; i += 512) A[i] = emb[i] + n2[i % 300];  // ev -> A
    if (t < 400) {
      int i = t / 20, j = t % 20;
      float a = adj[t] + (i == j ? 1.f : 0.f);
      an[t] = drt[i] * a * drt[j];
    }
    __syncthreads();
    int c = t & 255, half = t >> 8;
    {  // h1 = ev @ gc1_w  -> Bs
      float a2[10];
      #pragma unroll
      for (int j = 0; j < 10; ++j) a2[j] = 0.f;
      for (int d = 0; d < 300; ++d) {
        float wv2 = gc1_w[d*256 + c];
        #pragma unroll
        for (int j = 0; j < 10; ++j) a2[j] += A[(half + 2*j)*300 + d] * wv2;
      }
      __syncthreads();
      #pragma unroll
      for (int j = 0; j < 10; ++j) Bs[(half + 2*j)*256 + c] = a2[j];
    }
    __syncthreads();
    {  // g1 = relu(adjn @ h1) -> A
      #pragma unroll
      for (int j = 0; j < 10; ++j) {
        int n = half + 2*j;
        float a = 0.f;
        for (int m = 0; m < 20; ++m) a += an[n*20 + m] * Bs[m*256 + c];
        A[n*256 + c] = fmaxf(a, 0.f);
      }
    }
    __syncthreads();
    {  // h2 = g1 @ gc2_w -> Bs
      float a2[10];
      #pragma unroll
      for (int j = 0; j < 10; ++j) a2[j] = 0.f;
      for (int d = 0; d < 256; ++d) {
        float wv2 = gc2_w[d*256 + c];
        #pragma unroll
        for (int j = 0; j < 10; ++j) a2[j] += A[(half + 2*j)*256 + d] * wv2;
      }
      __syncthreads();
      #pragma unroll
      for (int j = 0; j < 10; ++j) Bs[(half + 2*j)*256 + c] = a2[j];
    }
    __syncthreads();
    {  // g2 = relu(adjn @ h2), rg = sum_n g2
      float gs = 0.f;
      #pragma unroll
      for (int j = 0; j < 10; ++j) {
        int n = half + 2*j;
        float a = 0.f;
        for (int m = 0; m < 20; ++m) a += an[n*20 + m] * Bs[m*256 + c];
        gs += fmaxf(a, 0.f);
      }
      rg2[t] = gs;
    }
    __syncthreads();
    if (t < 256) rg[t] = rg2[t] + rg2[t + 256];
    __syncthreads();
    {  // u = fw2 @ rg, per-wave rows, coalesced
      int wv = t >> 6, ll = t & 63;
      for (int oo = 0; oo < 32; ++oo) {
        int o = wv*32 + oo;
        float a = 0.f;
        #pragma unroll
        for (int kk = 0; kk < 4; ++kk) a += final_w[o*512 + 256 + kk*64 + ll] * rg[kk*64 + ll];
        #pragma unroll
        for (int off = 32; off; off >>= 1) a += __shfl_xor(a, off, 64);
        if (ll == 0) u[o] = a;
      }
    }
    return;
  }
  // ---- dgm + fmax/cmax reduce, b = blockIdx.x-1 ----
  int b = blockIdx.x - 1;
  float* xm = sp;            // 256
  float* redm = xm + 256;    // 8
  float* reds = redm + 8;    // 8
  if (t < 256) xm[t] = xsum[b*256 + t] * (1.f / 1024.f);
  if (t >= 256 && t < 272) {
    int m = t - 256; float fm = 0.f;
    for (int r = 0; r < 8; ++r) fm = fmaxf(fm, fmaxp[b*128 + r*16 + m]);
    fmaxb[b*16 + m] = fm;
  }
  if (t == 272) {
    float cm = 0.f;
    for (int r = 0; r < 8; ++r) cm = fmaxf(cm, cmaxp[b*8 + r]);
    cmaxb[b] = cm;
  }
  __syncthreads();
  if (t < 16) {
    float g = 0.f;
    for (int c = 0; c < 256; ++c) g += glob_w[t*256 + c] * xm[c];
    dgd[b*16 + t] = 0.5f * tanhf(0.5f * g);   // sigmoid(g) - 0.5
  }
  float v0 = s_raw[b*1024 + t], v1 = s_raw[b*1024 + 512 + t];
  float m = fmaxf(v0, v1);
  #pragma unroll
  for (int off = 32; off; off >>= 1) m = fmaxf(m, __shfl_xor(m, off, 64));
  int wv = t >> 6, ll = t & 63;
  if (ll == 0) redm[wv] = m;
  __syncthreads();
  float bm = redm[0];
  #pragma unroll
  for (int i = 1; i < 8; ++i) bm = fmaxf(bm, redm[i]);
  float e0 = __expf(v0 - bm), e1 = __expf(v1 - bm);
  float s2 = e0 + e1;
  #pragma unroll
  for (int off = 32; off; off >>= 1) s2 += __shfl_xor(s2, off, 64);
  if (ll == 0) reds[wv] = s2;
  __syncthreads();
  float tot = 0.f;
  #pragma unroll
  for (int i = 0; i < 8; ++i) tot += reds[i];
  float inv = 1.f / tot;
  mcol[b*1024 + t]       = e0 * inv;
  mcol[b*1024 + 512 + t] = e1 * inv;
}

// =================== LAUNCH C: k_main ===================
// S[p,q] = sum_m e'[p,m] f[m,q] (MFMA) + 0.5*a[p]*c[q]; E=exp(S-Mb); rowsum;
// S2u += E @ x_r; T = x_r - S2u/rs; out = relu(M@T^T + mcol*u + x).
// p-tile 32, grid (32,16) = 512 blocks (2/CU). A-frags direct from fBT (global),
// B-frags direct from xT bf16 (global). PT double-buffered: ONE barrier per st.
__global__ __launch_bounds__(256) void k_main(const float* x, const bf16_t* fB,
    const bf16_t* fBT, const bf16_t* xT, const bf16_t* M16, const float* fmaxb,
    const float* mcol, const float* u, const float* dgd, const float* csum,
    const float* cmaxb, float* out) {
  int flat = blockIdx.y * 32 + blockIdx.x;
  int b  = (flat & 7) * 2 + ((flat >> 3) >> 5);   // bijective XCD remap: 2 batches/XCD
  int p0 = ((flat >> 3) & 31) * 32;
  int t = threadIdx.x, w = t >> 6, l = t & 63, lr = l & 15, quad = l >> 4;
  int qh = w >> 1, ph = w & 1;
  __shared__ __align__(16) char smem[16896];       // union: {PT dbuf | e_s} / T_ls
  bf16_t* PT0  = (bf16_t*)smem;                    // 2 x [32][40]
  bf16_t* e_s  = (bf16_t*)(smem + 5120);           // [32][40] (m>=16 zero)
  bf16_t* T_ls = (bf16_t*)smem;                    // [32][264] phase 2
  __shared__ float Mb_s[32], fmax_s[16], u_s[256], rsinv_s[32], dgd_s[16];
  __shared__ float c_s[1024], ha_s[32], rs_s[2][32];
  const float*  xb   = x   + b*262144;
  const bf16_t* fBb  = fB  + b*16384;
  const bf16_t* fBTb = fBT + b*16384;
  const bf16_t* xTb  = xT  + b*262144;
  for (int i = t; i < 1280; i += 256) e_s[i] = (bf16_t)0.f;
  u_s[t] = u[t];
  for (int i = t; i < 1024; i += 256) c_s[i] = csum[b*1024 + i];
  if (t < 16) { fmax_s[t] = fmaxb[b*16 + t]; dgd_s[t] = dgd[b*16 + t]; }
  __syncthreads();
  for (int i = t; i < 512; i += 256) {       // e'[p,m] = x_phi * (sig(g[m])-0.5)
    int p = i >> 4, m = i & 15;
    e_s[p*40 + m] = (bf16_t)((float)fBb[p0*16 + i] * dgd_s[m]);
  }
  __syncthreads();
  if (t < 32) {
    float a = 0.f;
    #pragma unroll
    for (int m = 0; m < 16; ++m) a += (float)fBb[(p0 + t)*16 + m];
    float ha = 0.5f * a;
    ha_s[t] = ha;
    float mb = ha * cmaxb[b];
    #pragma unroll
    for (int m = 0; m < 16; ++m) mb += fmaxf((float)e_s[t*40 + m], 0.f) * fmax_s[m];
    Mb_s[t] = mb;  // exact upper bound on row max of S
  }
  __syncthreads();
  bf16x8 be = *(const bf16x8*)(e_s + (ph*16 + lr)*40 + quad*8);
  float mb_lane = Mb_s[ph*16 + lr];
  float ha_lane = ha_s[ph*16 + lr];
  float rs = 0.f;
  f32x4 acc[2][4];  // S2u[p = pf*16+quad*4+r][c = w*64+cf*16+lr]
  #pragma unroll
  for (int i = 0; i < 2; ++i)
    #pragma unroll
    for (int j = 0; j < 4; ++j) acc[i][j] = (f32x4){0.f, 0.f, 0.f, 0.f};
  bf16x8 a0{};
  if (quad < 2) a0 = *(const bf16x8*)(fBTb + (qh*16 + lr)*16 + quad*8);
  int cur = 0;
  for (int st = 0; st < 32; ++st) {
    f32x4 z = {0.f, 0.f, 0.f, 0.f};
    f32x4 s0 = MFMA(a0, be, z);   // D[q=st*32+qh*16+quad*4+r][p=ph*16+lr]
    if (st < 31 && quad < 2)
      a0 = *(const bf16x8*)(fBTb + ((st + 1)*32 + qh*16 + lr)*16 + quad*8);
    bf16_t* PTc = PT0 + cur*1280;
    bf16x4 pv;
    #pragma unroll
    for (int r = 0; r < 4; ++r) {
      float S0 = s0[r] + ha_lane * c_s[st*32 + qh*16 + quad*4 + r];
      float E0 = __expf(S0 - mb_lane);
      rs += E0;
      pv[r] = (bf16_t)E0;
    }
    *(bf16x4*)(PTc + (ph*16 + lr)*40 + qh*16 + quad*4) = pv;
    __syncthreads();
    bf16x8 ap0 = *(const bf16x8*)(PTc + lr*40 + quad*8);
    bf16x8 ap1 = *(const bf16x8*)(PTc + (16 + lr)*40 + quad*8);
    const bf16_t* xq = xTb + (w*64 + lr)*1024 + st*32 + quad*8;
    #pragma unroll
    for (int cf = 0; cf < 4; ++cf) {
      bf16x8 bv = *(const bf16x8*)(xq + cf*16*1024);   // x_r[q][c], q contiguous
      acc[0][cf] = MFMA(ap0, bv, acc[0][cf]);
      acc[1][cf] = MFMA(ap1, bv, acc[1][cf]);
    }
    cur ^= 1;
  }
  rs += __shfl_xor(rs, 16, 64);
  rs += __shfl_xor(rs, 32, 64);          // sum over quads: qh-half rowsum for p=ph*16+lr
  if (l < 16) rs_s[qh][ph*16 + lr] = rs;
  __syncthreads();   // rs staged; all PT/e_s reads drained -> T_ls may overwrite
  if (t < 32) rsinv_s[t] = 1.f / fmaxf(rs_s[0][t] + rs_s[1][t], 1e-30f);
  __syncthreads();
  #pragma unroll
  for (int pf = 0; pf < 2; ++pf)
    #pragma unroll
    for (int cf = 0; cf < 4; ++cf)
      #pragma unroll
      for (int r = 0; r < 4; ++r) {
        int p = pf*16 + quad*4 + r;
        int c = w*64 + cf*16 + lr;
        float tv = xb[(p0 + p)*256 + c] - acc[pf][cf][r] * rsinv_s[p];
        T_ls[p*264 + c] = (bf16_t)tv;    // spiral[p][c]
      }
  __syncthreads();
  f32x4 acc2[4][2];  // D2[o = w*64+of*16+quad*4+r][p = pf*16+lr]
  #pragma unroll
  for (int i = 0; i < 4; ++i)
    #pragma unroll
    for (int j = 0; j < 2; ++j) acc2[i][j] = (f32x4){0.f, 0.f, 0.f, 0.f};
  for (int c0 = 0; c0 < 256; c0 += 32) {
    bf16x8 am[4], bt[2];
    #pragma unroll
    for (int of = 0; of < 4; ++of)
      am[of] = *(const bf16x8*)(M16 + (w*64 + of*16 + lr)*256 + c0 + quad*8);
    #pragma unroll
    for (int pf = 0; pf < 2; ++pf)
      bt[pf] = *(const bf16x8*)(T_ls + (pf*16 + lr)*264 + c0 + quad*8);
    #pragma unroll
    for (int of = 0; of < 4; ++of)
      #pragma unroll
      for (int pf = 0; pf < 2; ++pf) acc2[of][pf] = MFMA(am[of], bt[pf], acc2[of][pf]);
  }
  float* outb = out + b*262144;
  #pragma unroll
  for (int of = 0; of < 4; ++of)
    #pragma unroll
    for (int pf = 0; pf < 2; ++pf)
      #pragma unroll
      for (int r = 0; r < 4; ++r) {
        int o = w*64 + of*16 + quad*4 + r;
        int pg = p0 + pf*16 + lr;
        float v = acc2[of][pf][r] + mcol[b*1024 + pg] * u_s[o] + xb[o*1024 + pg];
        outb[o*1024 + pg] = fmaxf(v, 0.f);
      }
}

// ---------------- launch ----------------

extern "C" void kernel_launch(void* const* d_in, const int* in_sizes, int n_in,
                              void* d_out, int out_size, void* d_ws, size_t ws_size,
                              hipStream_t stream) {
  (void)in_sizes; (void)n_in; (void)out_size; (void)ws_size;
  const float* x       = (const float*)d_in[0];
  const float* emb     = (const float*)d_in[1];
  const float* adj     = (const float*)d_in[2];
  const float* wq      = (const float*)d_in[3];
  const float* bq      = (const float*)d_in[4];
  const float* wk      = (const float*)d_in[5];
  const float* bk      = (const float*)d_in[6];
  const float* wv      = (const float*)d_in[7];
  const float* bv      = (const float*)d_in[8];
  const float* wo      = (const float*)d_in[9];
  const float* bo      = (const float*)d_in[10];
  const float* phi_w   = (const float*)d_in[11];
  const float* phi_b   = (const float*)d_in[12];
  const float* glob_w  = (const float*)d_in[13];
  const float* gc1_w   = (const float*)d_in[14];
  const float* gc2_w   = (const float*)d_in[15];
  const float* gw_w    = (const float*)d_in[16];
  const float* s2l_w   = (const float*)d_in[17];
  const float* final_w = (const float*)d_in[19];
  float* out = (float*)d_out;

  float* W = (float*)d_ws;
  float* qkv   = W + 0;        // 18000
  float* u     = W + 18048;    // 256
  float* xsum  = W + 18304;    // 4096
  float* s_raw = W + 22400;    // 16384
  float* mcol  = W + 38784;    // 16384
  float* fmaxb = W + 55168;    // 256
  float* dgd   = W + 55424;    // 256
  float* csum  = W + 55680;    // 16384
  float* cmaxb = W + 72064;    // 16
  float* fmaxp = W + 72128;    // 2048
  float* cmaxp = W + 74176;    // 128
  bf16_t* M16 = (bf16_t*)((char*)d_ws + 327680);   // 128 KB
  bf16_t* fB  = (bf16_t*)((char*)d_ws + 458752);   // 512 KB (m-major raw)
  bf16_t* fBT = (bf16_t*)((char*)d_ws + 983040);   // 512 KB (q-major)
  bf16_t* xT  = (bf16_t*)((char*)d_ws + 1507328);  // 8 MB  (x transposed bf16)
  // total ws usage ~9.9 MB

  k_front<<<1484, 256, 0, stream>>>(final_w, gw_w, emb, wq, bq, wk, bk, wv, bv, x,
                                    phi_w, phi_b, s2l_w,
                                    M16, qkv, fB, fBT, s_raw, xsum, csum,
                                    fmaxp, cmaxp, xT);
  k_mid<<<17, 512, 0, stream>>>(emb, adj, wo, bo, qkv, gc1_w, gc2_w, final_w,
                                glob_w, xsum, s_raw, fmaxp, cmaxp,
                                u, dgd, mcol, fmaxb, cmaxb);
  k_main<<<dim3(32, 16), 256, 0, stream>>>(x, fB, fBT, xT, M16, fmaxb, mcol, u,
                                           dgd, csum, cmaxb, out);
}

// Round 3
// 271.222 us; speedup vs baseline: 1.0999x; 1.0383x over previous
//
#include <hip/hip_runtime.h>
#include <hip/hip_bf16.h>

// Inputs/outputs are FLOAT32 (reference dtype). bf16 used only internally for MFMA.
typedef __bf16 bf16_t;
typedef bf16_t bf16x8 __attribute__((ext_vector_type(8)));
typedef bf16_t bf16x4 __attribute__((ext_vector_type(4)));
typedef float  f32x4  __attribute__((ext_vector_type(4)));

#define MFMA(a,b,c) __builtin_amdgcn_mfma_f32_16x16x32_bf16((a),(b),(c),0,0,0)

// =================== LAUNCH A: k_front ===================
// roles by blockIdx.x:
//   [0,256)      : M = final_w[:, :256] @ gw_w  (bf16)
//   [256,316)    : qkv = emb @ {wq,wk,wv} + bias
//   [316,460)    : phis (9 roles x 16 b): fB, fBT, s_raw, csum, fmax/cmax partials, xsum
//   [460,1484)   : xT transpose: x raw [1024q][256c] fp32 -> xT [256c][1024q] bf16
//   [1484,1504)  : E1 = emb @ gc1_w           [20][256]
//   [1504,1805)  : WG1 = wo @ gc1_w [300][256]; row 300 = bg1 = bo @ gc1_w
__global__ __launch_bounds__(256) void k_front(
    const float* final_w, const float* gw_w, const float* emb,
    const float* wq, const float* bq, const float* wk, const float* bk,
    const float* wv, const float* bvv, const float* x,
    const float* phi_w, const float* phi_b, const float* s2l_w,
    const float* gc1_w, const float* wo, const float* bo,
    bf16_t* M16, float* qkv, bf16_t* fB, bf16_t* fBT, float* s_raw,
    float* xsum, float* csum, float* fmaxp, float* cmaxp, bf16_t* xT,
    float* E1, float* WG1, float* bg1) {
  __shared__ __align__(16) char sp[27648];
  int bid = blockIdx.x, t = threadIdx.x;
  if (bid < 256) {                       // ---- k_M ----
    float* fw = (float*)sp;
    int o = bid, c = t;
    fw[c] = final_w[o*512 + c];
    __syncthreads();
    float acc = 0.f;
    for (int k = 0; k < 256; ++k) acc += fw[k] * gw_w[k*256 + c];
    M16[o*256 + c] = (bf16_t)acc;
    return;
  }
  if (bid < 316) {                       // ---- k_qkv ----
    int id = bid - 256;
    int mat = id / 20, row = id % 20;
    const float* W  = mat == 0 ? wq : (mat == 1 ? wk : wv);
    const float* Bb = mat == 0 ? bq : (mat == 1 ? bk : bvv);
    float* er = (float*)sp;
    for (int i = t; i < 300; i += 256) er[i] = emb[row*300 + i];
    __syncthreads();
    for (int o = t; o < 300; o += 256) {
      float acc = Bb[o];
      for (int d = 0; d < 300; ++d) acc += er[d] * W[d*300 + o];
      qkv[(mat*20 + row)*300 + o] = acc;
    }
    return;
  }
  if (bid < 460) {                       // ---- k_phis ----
    int id = bid - 316;
    int b = id / 9, role = id % 9;
    const float* xb = x + b*262144;
    if (role == 8) {
      int wv2 = t >> 6, lane = t & 63;
      for (int c = wv2; c < 256; c += 4) {
        float acc = 0.f;
        const float* p = xb + c*1024 + lane;
        #pragma unroll
        for (int k = 0; k < 16; ++k) acc += p[k*64];
        #pragma unroll
        for (int off = 32; off; off >>= 1) acc += __shfl_down(acc, off, 64);
        if (lane == 0) xsum[b*256 + c] = acc;
      }
      return;
    }
    float* pw = (float*)sp;              // 4096
    float* wi = pw + 4096;               // 256
    float* pb = wi + 256;                // 16
    float* phs = pb + 16;                // [128][18]
    unsigned* fmu = (unsigned*)(phs + 2304);  // 16
    unsigned* cmu = fmu + 16;            // 1
    for (int i = t; i < 4096; i += 256) pw[i] = phi_w[i];
    wi[t] = s2l_w[t];
    if (t < 16) { pb[t] = phi_b[t]; fmu[t] = 0u; }
    if (t == 0) cmu[0] = 0u;
    __syncthreads();
    int hwl = t & 127, half = t >> 7;
    int hw = role*128 + hwl;
    float ph[16];
    #pragma unroll
    for (int o = 0; o < 16; ++o) ph[o] = 0.f;
    float sacc = 0.f;
    for (int ci = 0; ci < 128; ++ci) {
      int c = half*128 + ci;
      float xv = xb[c*1024 + hw];
      sacc += wi[c] * xv;
      #pragma unroll
      for (int o = 0; o < 16; ++o) ph[o] += pw[o*256 + c] * xv;
    }
    if (half == 0) {
      #pragma unroll
      for (int o = 0; o < 16; ++o) phs[hwl*18 + o] = ph[o];
      phs[hwl*18 + 16] = sacc;
    }
    __syncthreads();
    if (half == 1) {
      #pragma unroll
      for (int o = 0; o < 16; ++o) phs[hwl*18 + o] += ph[o];
      s_raw[b*1024 + hw] = phs[hwl*18 + 16] + sacc;
    }
    __syncthreads();
    float csacc = 0.f;
    #pragma unroll
    for (int i = 0; i < 8; ++i) {
      int j = i*256 + t;
      int o = j >> 7, hl = j & 127;
      float val = fmaxf(phs[hl*18 + o] + pb[o], 0.f);
      bf16_t bv16 = (bf16_t)val;
      atomicMax(&fmu[o], __float_as_uint((float)bv16));
      fB [b*16384 + o*1024 + role*128 + hl] = bv16;            // m-major (raw)
      fBT[b*16384 + (role*128 + hl)*16 + o] = bv16;            // q-major
      csacc += (float)bv16;
    }
    if (half == 0) phs[hwl*18 + 17] = csacc;
    __syncthreads();
    if (half == 1) {
      float cs = phs[hwl*18 + 17] + csacc;
      csum[b*1024 + hw] = cs;
      atomicMax(cmu, __float_as_uint(cs));
    }
    if (t < 16) fmaxp[b*128 + role*16 + t] = __uint_as_float(fmu[t]);
    __syncthreads();
    if (t == 0) cmaxp[b*8 + role] = __uint_as_float(cmu[0]);
    return;
  }
  if (bid < 1484) {                      // ---- k_xt ----
    int id = bid - 460;                  // 0..1023
    int bb = id >> 6, tile = id & 63;
    int q0 = (tile >> 2) * 64, c0 = (tile & 3) * 64;
    bf16_t* tl = (bf16_t*)sp;            // [64][74]
    const float* xbb = x + bb*262144;
    #pragma unroll
    for (int k = 0; k < 16; ++k) {
      int idx = k*256 + t, qi = idx >> 6, ci = idx & 63;
      tl[ci*74 + qi] = (bf16_t)xbb[(q0 + qi)*256 + c0 + ci];
    }
    __syncthreads();
    #pragma unroll
    for (int k = 0; k < 16; ++k) {
      int idx = k*256 + t, ci = idx >> 6, qi = idx & 63;
      xT[bb*262144 + (c0 + ci)*1024 + q0 + qi] = tl[ci*74 + qi];
    }
    return;
  }
  if (bid < 1504) {                      // ---- E1 = emb @ gc1_w ----
    int n = bid - 1484;
    float* er = (float*)sp;
    for (int i = t; i < 300; i += 256) er[i] = emb[n*300 + i];
    __syncthreads();
    float acc = 0.f;
    for (int d = 0; d < 300; ++d) acc += er[d] * gc1_w[d*256 + t];
    E1[n*256 + t] = acc;
    return;
  }
  {                                      // ---- WG1 rows / bg1 ----
    int d0 = bid - 1504;                 // 0..300
    float* er = (float*)sp;
    if (d0 < 300) { for (int i = t; i < 300; i += 256) er[i] = wo[d0*300 + i]; }
    else          { for (int i = t; i < 300; i += 256) er[i] = bo[i]; }
    __syncthreads();
    float acc = 0.f;
    for (int e = 0; e < 300; ++e) acc += er[e] * gc1_w[e*256 + t];
    if (d0 < 300) WG1[d0*256 + t] = acc; else bg1[t] = acc;
    return;
  }
}

// =================== LAUNCH B: k_mid1 (18 blocks x 512) ===================
// block 0 : att softmax -> wsum -> n1
// block 1 : adjn/rsA from adj; AE1 = adjn @ E1
// blocks 2-17: dgm for b = blockIdx.x-2, plus fmax/cmax partial reduction
__global__ __launch_bounds__(512) void k_mid1(
    const float* emb, const float* adj, const float* qkv, const float* E1,
    const float* glob_w, const float* xsum, const float* s_raw,
    const float* fmaxp, const float* cmaxp,
    float* n1g, float* adjng, float* rsAg, float* AE1g,
    float* dgd, float* mcol, float* fmaxb, float* cmaxb) {
  __shared__ __align__(16) float sp[12480];
  int t = threadIdx.x;
  if (blockIdx.x == 0) {                 // ---- attention -> n1 ----
    float* A  = sp;            // 6000 q
    float* Bs = A + 6000;      // 6000 k
    float* att  = Bs + 6000;   // 400
    float* wsum = att + 400;   // 20
    for (int i = t; i < 6000; i += 512) { A[i] = qkv[i]; Bs[i] = qkv[6000 + i]; }
    __syncthreads();
    if (t < 400) {
      int i = t / 20, j = t % 20;
      float acc = 0.f;
      for (int d = 0; d < 300; ++d) acc += A[i*300 + d] * Bs[j*300 + d];
      att[t] = acc * 0.05773502691896258f;  // 1/sqrt(300)
    }
    __syncthreads();
    if (t < 20) {
      float m = -1e30f;
      for (int j = 0; j < 20; ++j) m = fmaxf(m, att[t*20 + j]);
      float s = 0.f;
      for (int j = 0; j < 20; ++j) { float e = __expf(att[t*20 + j] - m); att[t*20 + j] = e; s += e; }
      float inv = 1.f / s;
      for (int j = 0; j < 20; ++j) att[t*20 + j] *= inv;
    }
    __syncthreads();
    if (t < 20) {
      float s = 0.f;
      for (int i = 0; i < 20; ++i) s += att[i*20 + t];
      wsum[t] = s * 0.05f;
    }
    __syncthreads();
    if (t < 300) {
      const float* v = qkv + 12000;
      float acc = 0.f;
      for (int j = 0; j < 20; ++j) acc += wsum[j] * v[j*300 + t];
      n1g[t] = acc;
    }
    return;
  }
  if (blockIdx.x == 1) {                 // ---- adjn / rsA / AE1 ----
    float* drt = sp;           // 20
    float* an  = sp + 32;      // 400
    if (t < 20) {
      float s = 1.f;
      for (int j = 0; j < 20; ++j) s += adj[t*20 + j];
      drt[t] = rsqrtf(s);
    }
    __syncthreads();
    if (t < 400) {
      int i = t / 20, j = t % 20;
      float a = adj[t] + (i == j ? 1.f : 0.f);
      float v = drt[i] * a * drt[j];
      an[t] = v;
      adjng[t] = v;
    }
    __syncthreads();
    if (t < 20) {
      float s = 0.f;
      for (int m = 0; m < 20; ++m) s += an[t*20 + m];
      rsAg[t] = s;
    }
    if (t < 256) {
      float e[20];
      #pragma unroll
      for (int m = 0; m < 20; ++m) e[m] = E1[m*256 + t];
      for (int n = 0; n < 20; ++n) {
        float acc = 0.f;
        #pragma unroll
        for (int m = 0; m < 20; ++m) acc += an[n*20 + m] * e[m];
        AE1g[n*256 + t] = acc;
      }
    }
    return;
  }
  // ---- dgm + fmax/cmax reduce, b = blockIdx.x-2 ----
  int b = blockIdx.x - 2;
  float* xm = sp;            // 256
  float* redm = xm + 256;    // 8
  float* reds = redm + 8;    // 8
  if (t < 256) xm[t] = xsum[b*256 + t] * (1.f / 1024.f);
  if (t >= 256 && t < 272) {
    int m = t - 256; float fm = 0.f;
    for (int r = 0; r < 8; ++r) fm = fmaxf(fm, fmaxp[b*128 + r*16 + m]);
    fmaxb[b*16 + m] = fm;
  }
  if (t == 272) {
    float cm = 0.f;
    for (int r = 0; r < 8; ++r) cm = fmaxf(cm, cmaxp[b*8 + r]);
    cmaxb[b] = cm;
  }
  __syncthreads();
  if (t < 16) {
    float g = 0.f;
    for (int c = 0; c < 256; ++c) g += glob_w[t*256 + c] * xm[c];
    dgd[b*16 + t] = 0.5f * tanhf(0.5f * g);   // sigmoid(g) - 0.5
  }
  float v0 = s_raw[b*1024 + t], v1 = s_raw[b*1024 + 512 + t];
  float m = fmaxf(v0, v1);
  #pragma unroll
  for (int off = 32; off; off >>= 1) m = fmaxf(m, __shfl_xor(m, off, 64));
  int wv = t >> 6, ll = t & 63;
  if (ll == 0) redm[wv] = m;
  __syncthreads();
  float bm = redm[0];
  #pragma unroll
  for (int i = 1; i < 8; ++i) bm = fmaxf(bm, redm[i]);
  float e0 = __expf(v0 - bm), e1 = __expf(v1 - bm);
  float s2 = e0 + e1;
  #pragma unroll
  for (int off = 32; off; off >>= 1) s2 += __shfl_xor(s2, off, 64);
  if (ll == 0) reds[wv] = s2;
  __syncthreads();
  float tot = 0.f;
  #pragma unroll
  for (int i = 0; i < 8; ++i) tot += reds[i];
  float inv = 1.f / tot;
  mcol[b*1024 + t]       = e0 * inv;
  mcol[b*1024 + 512 + t] = e1 * inv;
}

// =================== LAUNCH C: k_w1 (8 blocks) ===================
// w1[c] = bg1[c] + sum_d n1[d] * WG1[d,c]; block owns 32 c's, 8 d-parts.
__global__ __launch_bounds__(256) void k_w1(const float* n1g, const float* WG1,
                                            const float* bg1, float* w1g) {
  __shared__ float n1s[304];
  __shared__ float red[8][32];
  int t = threadIdx.x, c0 = blockIdx.x * 32, cl = t & 31, dp = t >> 5;
  for (int i = t; i < 300; i += 256) n1s[i] = n1g[i];
  __syncthreads();
  float acc = 0.f;
  for (int d = dp; d < 300; d += 8) acc += n1s[d] * WG1[d*256 + c0 + cl];
  red[dp][cl] = acc;
  __syncthreads();
  if (t < 32) {
    float s = bg1[c0 + t];
    #pragma unroll
    for (int k = 0; k < 8; ++k) s += red[k][t];
    w1g[c0 + t] = s;
  }
}

// =================== LAUNCH D: k_g (8 blocks) ===================
// g1 = relu(AE1 + rsA (x) w1) (full, LDS); h2[:,slice] = g1 @ gc2_w[:,slice];
// g2[:,slice] = relu(adjn @ h2); rg[slice] = sum_n g2.
__global__ __launch_bounds__(256) void k_g(const float* AE1g, const float* rsAg,
    const float* w1g, const float* adjng, const float* gc2_w, float* rg) {
  __shared__ float w1s[256], adjns[400], rsAs[20], h2s[640];
  __shared__ float g1s[5120];
  int t = threadIdx.x, c0 = blockIdx.x * 32;
  w1s[t] = w1g[t];
  for (int i = t; i < 400; i += 256) adjns[i] = adjng[i];
  if (t < 20) rsAs[t] = rsAg[t];
  __syncthreads();
  for (int i = t; i < 5120; i += 256) {
    int n = i >> 8;
    g1s[i] = fmaxf(AE1g[i] + rsAs[n] * w1s[i & 255], 0.f);
  }
  __syncthreads();
  int cl = t & 31, ng = t >> 3 >> 2;   // ng = t>>5
  float a0 = 0.f, a1 = 0.f, a2 = 0.f;
  for (int d = 0; d < 256; ++d) {
    float wv = gc2_w[d*256 + c0 + cl];
    a0 += g1s[ng*256 + d] * wv;
    a1 += g1s[(ng + 8)*256 + d] * wv;
    if (ng < 4) a2 += g1s[(ng + 16)*256 + d] * wv;
  }
  h2s[ng*32 + cl] = a0;
  h2s[(ng + 8)*32 + cl] = a1;
  if (ng < 4) h2s[(ng + 16)*32 + cl] = a2;
  __syncthreads();
  if (t < 32) {
    float rga = 0.f;
    for (int n = 0; n < 20; ++n) {
      float acc = 0.f;
      #pragma unroll
      for (int m = 0; m < 20; ++m) acc += adjns[n*20 + m] * h2s[m*32 + t];
      rga += fmaxf(acc, 0.f);
    }
    rg[c0 + t] = rga;
  }
}

// =================== LAUNCH E: k_u (8 blocks) ===================
// u[o] = sum_k final_w[o,256+k] * rg[k]; block owns 32 o's, 8 k-parts.
__global__ __launch_bounds__(256) void k_u(const float* final_w, const float* rg,
                                           float* ug) {
  __shared__ float rgs[256];
  __shared__ float red[8][32];
  int t = threadIdx.x, o0 = blockIdx.x * 32, ol = t & 31, kp = t >> 5;
  rgs[t] = rg[t];
  __syncthreads();
  const float* fw = final_w + (o0 + ol)*512 + 256 + kp*32;
  float acc = 0.f;
  #pragma unroll
  for (int kk = 0; kk < 32; ++kk) acc += fw[kk] * rgs[kp*32 + kk];
  red[kp][ol] = acc;
  __syncthreads();
  if (t < 32) {
    float s = 0.f;
    #pragma unroll
    for (int k = 0; k < 8; ++k) s += red[k][t];
    ug[o0 + t] = s;
  }
}

// =================== LAUNCH F: k_main ===================
// S[p,q] = sum_m e'[p,m] f[m,q] (MFMA) + 0.5*a[p]*c[q]; E=exp(S-Mb); rowsum;
// S2u += E @ x_r; T = x_r - S2u/rs; out = relu(M@T^T + mcol*u + x).
// p-tile 32, grid (32,16) = 512 blocks (2/CU). A-frags direct from fBT (global),
// B-frags direct from xT bf16 (global). PT double-buffered: ONE barrier per st.
__global__ __launch_bounds__(256) void k_main(const float* x, const bf16_t* fB,
    const bf16_t* fBT, const bf16_t* xT, const bf16_t* M16, const float* fmaxb,
    const float* mcol, const float* u, const float* dgd, const float* csum,
    const float* cmaxb, float* out) {
  int flat = blockIdx.y * 32 + blockIdx.x;
  int b  = (flat & 7) * 2 + ((flat >> 3) >> 5);   // bijective XCD remap: 2 batches/XCD
  int p0 = ((flat >> 3) & 31) * 32;
  int t = threadIdx.x, w = t >> 6, l = t & 63, lr = l & 15, quad = l >> 4;
  int qh = w >> 1, ph = w & 1;
  __shared__ __align__(16) char smem[16896];       // union: {PT dbuf | e_s} / T_ls
  bf16_t* PT0  = (bf16_t*)smem;                    // 2 x [32][40]
  bf16_t* e_s  = (bf16_t*)(smem + 5120);           // [32][40] (m>=16 zero)
  bf16_t* T_ls = (bf16_t*)smem;                    // [32][264] phase 2
  __shared__ float Mb_s[32], fmax_s[16], u_s[256], rsinv_s[32], dgd_s[16];
  __shared__ float c_s[1024], ha_s[32], rs_s[2][32];
  const float*  xb   = x   + b*262144;
  const bf16_t* fBb  = fB  + b*16384;
  const bf16_t* fBTb = fBT + b*16384;
  const bf16_t* xTb  = xT  + b*262144;
  for (int i = t; i < 1280; i += 256) e_s[i] = (bf16_t)0.f;
  u_s[t] = u[t];
  for (int i = t; i < 1024; i += 256) c_s[i] = csum[b*1024 + i];
  if (t < 16) { fmax_s[t] = fmaxb[b*16 + t]; dgd_s[t] = dgd[b*16 + t]; }
  __syncthreads();
  for (int i = t; i < 512; i += 256) {       // e'[p,m] = x_phi * (sig(g[m])-0.5)
    int p = i >> 4, m = i & 15;
    e_s[p*40 + m] = (bf16_t)((float)fBb[p0*16 + i] * dgd_s[m]);
  }
  __syncthreads();
  if (t < 32) {
    float a = 0.f;
    #pragma unroll
    for (int m = 0; m < 16; ++m) a += (float)fBb[(p0 + t)*16 + m];
    float ha = 0.5f * a;
    ha_s[t] = ha;
    float mb = ha * cmaxb[b];
    #pragma unroll
    for (int m = 0; m < 16; ++m) mb += fmaxf((float)e_s[t*40 + m], 0.f) * fmax_s[m];
    Mb_s[t] = mb;  // exact upper bound on row max of S
  }
  __syncthreads();
  bf16x8 be = *(const bf16x8*)(e_s + (ph*16 + lr)*40 + quad*8);
  float mb_lane = Mb_s[ph*16 + lr];
  float ha_lane = ha_s[ph*16 + lr];
  float rs = 0.f;
  f32x4 acc[2][4];  // S2u[p = pf*16+quad*4+r][c = w*64+cf*16+lr]
  #pragma unroll
  for (int i = 0; i < 2; ++i)
    #pragma unroll
    for (int j = 0; j < 4; ++j) acc[i][j] = (f32x4){0.f, 0.f, 0.f, 0.f};
  bf16x8 a0{};
  if (quad < 2) a0 = *(const bf16x8*)(fBTb + (qh*16 + lr)*16 + quad*8);
  int cur = 0;
  for (int st = 0; st < 32; ++st) {
    f32x4 z = {0.f, 0.f, 0.f, 0.f};
    f32x4 s0 = MFMA(a0, be, z);   // D[q=st*32+qh*16+quad*4+r][p=ph*16+lr]
    if (st < 31 && quad < 2)
      a0 = *(const bf16x8*)(fBTb + ((st + 1)*32 + qh*16 + lr)*16 + quad*8);
    bf16_t* PTc = PT0 + cur*1280;
    bf16x4 pv;
    #pragma unroll
    for (int r = 0; r < 4; ++r) {
      float S0 = s0[r] + ha_lane * c_s[st*32 + qh*16 + quad*4 + r];
      float E0 = __expf(S0 - mb_lane);
      rs += E0;
      pv[r] = (bf16_t)E0;
    }
    *(bf16x4*)(PTc + (ph*16 + lr)*40 + qh*16 + quad*4) = pv;
    __syncthreads();
    bf16x8 ap0 = *(const bf16x8*)(PTc + lr*40 + quad*8);
    bf16x8 ap1 = *(const bf16x8*)(PTc + (16 + lr)*40 + quad*8);
    const bf16_t* xq = xTb + (w*64 + lr)*1024 + st*32 + quad*8;
    #pragma unroll
    for (int cf = 0; cf < 4; ++cf) {
      bf16x8 bv = *(const bf16x8*)(xq + cf*16*1024);   // x_r[q][c], q contiguous
      acc[0][cf] = MFMA(ap0, bv, acc[0][cf]);
      acc[1][cf] = MFMA(ap1, bv, acc[1][cf]);
    }
    cur ^= 1;
  }
  rs += __shfl_xor(rs, 16, 64);
  rs += __shfl_xor(rs, 32, 64);          // sum over quads: qh-half rowsum for p=ph*16+lr
  if (l < 16) rs_s[qh][ph*16 + lr] = rs;
  __syncthreads();   // rs staged; all PT/e_s reads drained -> T_ls may overwrite
  if (t < 32) rsinv_s[t] = 1.f / fmaxf(rs_s[0][t] + rs_s[1][t], 1e-30f);
  __syncthreads();
  #pragma unroll
  for (int pf = 0; pf < 2; ++pf)
    #pragma unroll
    for (int cf = 0; cf < 4; ++cf)
      #pragma unroll
      for (int r = 0; r < 4; ++r) {
        int p = pf*16 + quad*4 + r;
        int c = w*64 + cf*16 + lr;
        float tv = xb[(p0 + p)*256 + c] - acc[pf][cf][r] * rsinv_s[p];
        T_ls[p*264 + c] = (bf16_t)tv;    // spiral[p][c]
      }
  __syncthreads();
  f32x4 acc2[4][2];  // D2[o = w*64+of*16+quad*4+r][p = pf*16+lr]
  #pragma unroll
  for (int i = 0; i < 4; ++i)
    #pragma unroll
    for (int j = 0; j < 2; ++j) acc2[i][j] = (f32x4){0.f, 0.f, 0.f, 0.f};
  for (int c0 = 0; c0 < 256; c0 += 32) {
    bf16x8 am[4], bt[2];
    #pragma unroll
    for (int of = 0; of < 4; ++of)
      am[of] = *(const bf16x8*)(M16 + (w*64 + of*16 + lr)*256 + c0 + quad*8);
    #pragma unroll
    for (int pf = 0; pf < 2; ++pf)
      bt[pf] = *(const bf16x8*)(T_ls + (pf*16 + lr)*264 + c0 + quad*8);
    #pragma unroll
    for (int of = 0; of < 4; ++of)
      #pragma unroll
      for (int pf = 0; pf < 2; ++pf) acc2[of][pf] = MFMA(am[of], bt[pf], acc2[of][pf]);
  }
  float* outb = out + b*262144;
  #pragma unroll
  for (int of = 0; of < 4; ++of)
    #pragma unroll
    for (int pf = 0; pf < 2; ++pf)
      #pragma unroll
      for (int r = 0; r < 4; ++r) {
        int o = w*64 + of*16 + quad*4 + r;
        int pg = p0 + pf*16 + lr;
        float v = acc2[of][pf][r] + mcol[b*1024 + pg] * u_s[o] + xb[o*1024 + pg];
        outb[o*1024 + pg] = fmaxf(v, 0.f);
      }
}

// ---------------- launch ----------------

extern "C" void kernel_launch(void* const* d_in, const int* in_sizes, int n_in,
                              void* d_out, int out_size, void* d_ws, size_t ws_size,
                              hipStream_t stream) {
  (void)in_sizes; (void)n_in; (void)out_size; (void)ws_size;
  const float* x       = (const float*)d_in[0];
  const float* emb     = (const float*)d_in[1];
  const float* adj     = (const float*)d_in[2];
  const float* wq      = (const float*)d_in[3];
  const float* bq      = (const float*)d_in[4];
  const float* wk      = (const float*)d_in[5];
  const float* bk      = (const float*)d_in[6];
  const float* wv      = (const float*)d_in[7];
  const float* bv      = (const float*)d_in[8];
  const float* wo      = (const float*)d_in[9];
  const float* bo      = (const float*)d_in[10];
  const float* phi_w   = (const float*)d_in[11];
  const float* phi_b   = (const float*)d_in[12];
  const float* glob_w  = (const float*)d_in[13];
  const float* gc1_w   = (const float*)d_in[14];
  const float* gc2_w   = (const float*)d_in[15];
  const float* gw_w    = (const float*)d_in[16];
  const float* s2l_w   = (const float*)d_in[17];
  const float* final_w = (const float*)d_in[19];
  float* out = (float*)d_out;

  float* W = (float*)d_ws;
  float* qkv   = W + 0;        // 18000
  float* u     = W + 18048;    // 256
  float* xsum  = W + 18304;    // 4096
  float* s_raw = W + 22400;    // 16384
  float* mcol  = W + 38784;    // 16384
  float* fmaxb = W + 55168;    // 256
  float* dgd   = W + 55424;    // 256
  float* csum  = W + 55680;    // 16384
  float* cmaxb = W + 72064;    // 64
  float* fmaxp = W + 72128;    // 2048
  float* cmaxp = W + 74176;    // 128
  float* E1    = W + 74304;    // 5120
  float* WG1   = W + 79424;    // 76800
  float* bg1   = W + 156224;   // 256
  float* n1    = W + 156480;   // 320
  float* adjn  = W + 156800;   // 448
  float* rsA   = W + 157248;   // 64
  float* AE1   = W + 157312;   // 5120
  float* w1    = W + 162432;   // 256
  float* rg    = W + 162688;   // 256 -> ends 162944 floats (651776 B)
  bf16_t* M16 = (bf16_t*)((char*)d_ws + 655360);   // 128 KB
  bf16_t* fB  = (bf16_t*)((char*)d_ws + 786432);   // 512 KB (m-major raw)
  bf16_t* fBT = (bf16_t*)((char*)d_ws + 1310720);  // 512 KB (q-major)
  bf16_t* xT  = (bf16_t*)((char*)d_ws + 1835008);  // 8 MB  (x transposed bf16)
  // total ws usage ~9.75 MB

  k_front<<<1805, 256, 0, stream>>>(final_w, gw_w, emb, wq, bq, wk, bk, wv, bv, x,
                                    phi_w, phi_b, s2l_w, gc1_w, wo, bo,
                                    M16, qkv, fB, fBT, s_raw, xsum, csum,
                                    fmaxp, cmaxp, xT, E1, WG1, bg1);
  k_mid1<<<18, 512, 0, stream>>>(emb, adj, qkv, E1, glob_w, xsum, s_raw,
                                 fmaxp, cmaxp,
                                 n1, adjn, rsA, AE1, dgd, mcol, fmaxb, cmaxb);
  k_w1<<<8, 256, 0, stream>>>(n1, WG1, bg1, w1);
  k_g <<<8, 256, 0, stream>>>(AE1, rsA, w1, adjn, gc2_w, rg);
  k_u <<<8, 256, 0, stream>>>(final_w, rg, u);
  k_main<<<dim3(32, 16), 256, 0, stream>>>(x, fB, fBT, xT, M16, fmaxb, mcol, u,
                                           dgd, csum, cmaxb, out);
}

// Round 5
// 237.748 us; speedup vs baseline: 1.2547x; 1.1408x over previous
//
#include <hip/hip_runtime.h>
#include <hip/hip_bf16.h>

// Inputs/outputs are FLOAT32 (reference dtype). bf16 used only internally for MFMA.
typedef __bf16 bf16_t;
typedef bf16_t bf16x8 __attribute__((ext_vector_type(8)));
typedef bf16_t bf16x4 __attribute__((ext_vector_type(4)));
typedef float  f32x4  __attribute__((ext_vector_type(4)));

#define MFMA(a,b,c) __builtin_amdgcn_mfma_f32_16x16x32_bf16((a),(b),(c),0,0,0)

// =================== LAUNCH A: k_front (1789 blocks) ===================
// roles by blockIdx.x:
//   [0,256)     : M = final_w[:, :256] @ gw_w  (bf16)
//   [256,316)   : qkv = emb @ {wq,wk,wv} + bias
//   [316,444)   : phis (8 roles x 16 b): fB, fBT, s_raw, csum, fmax/cmax, xsump
//   [444,464)   : E1 = emb @ gc1_w  [20][256]
//   [464,765)   : WG1 = wo @ gc1_w [300][256]; row 300 = bg1 = bo @ gc1_w
//   [765,1789)  : xT transpose: raw [1024q][256c] fp32 -> xT [256c][1024q] bf16
__global__ __launch_bounds__(256) void k_front(
    const float* final_w, const float* gw_w, const float* emb,
    const float* wq, const float* bq, const float* wk, const float* bk,
    const float* wv, const float* bvv, const float* x,
    const float* phi_w, const float* phi_b, const float* s2l_w,
    const float* gc1_w, const float* wo, const float* bo,
    bf16_t* M16, float* qkv, bf16_t* fB, bf16_t* fBT, float* s_raw,
    float* xsump, float* csum, float* fmaxp, float* cmaxp, bf16_t* xT,
    float* E1, float* WG1, float* bg1) {
  __shared__ __align__(16) char sp[27648];
  int bid = blockIdx.x, t = threadIdx.x;
  if (bid < 256) {                       // ---- k_M ----
    float* fw = (float*)sp;
    int o = bid, c = t;
    fw[c] = final_w[o*512 + c];
    __syncthreads();
    float acc = 0.f;
    for (int k = 0; k < 256; ++k) acc += fw[k] * gw_w[k*256 + c];
    M16[o*256 + c] = (bf16_t)acc;
    return;
  }
  if (bid < 316) {                       // ---- k_qkv ----
    int id = bid - 256;
    int mat = id / 20, row = id % 20;
    const float* W  = mat == 0 ? wq : (mat == 1 ? wk : wv);
    const float* Bb = mat == 0 ? bq : (mat == 1 ? bk : bvv);
    float* er = (float*)sp;
    for (int i = t; i < 300; i += 256) er[i] = emb[row*300 + i];
    __syncthreads();
    for (int o = t; o < 300; o += 256) {
      float acc = Bb[o];
      for (int d = 0; d < 300; ++d) acc += er[d] * W[d*300 + o];
      qkv[(mat*20 + row)*300 + o] = acc;
    }
    return;
  }
  if (bid < 444) {                       // ---- k_phis ----
    int id = bid - 316;
    int b = id >> 3, role = id & 7;
    const float* xb = x + b*262144;
    float* pw = (float*)sp;              // 4096
    float* wi = pw + 4096;               // 256
    float* pb = wi + 256;                // 16
    float* phs = pb + 16;                // [128][18]
    unsigned* fmu = (unsigned*)(phs + 2304);  // 16
    unsigned* cmu = fmu + 16;            // 1
    for (int i = t; i < 4096; i += 256) pw[i] = phi_w[i];
    wi[t] = s2l_w[t];
    if (t < 16) { pb[t] = phi_b[t]; fmu[t] = 0u; }
    if (t == 0) cmu[0] = 0u;
    __syncthreads();
    int hwl = t & 127, half = t >> 7;
    int hw = role*128 + hwl;
    float ph[16];
    #pragma unroll
    for (int o = 0; o < 16; ++o) ph[o] = 0.f;
    float sacc = 0.f;
    for (int ci = 0; ci < 128; ++ci) {
      int c = half*128 + ci;
      float xv = xb[c*1024 + hw];
      sacc += wi[c] * xv;
      #pragma unroll
      for (int o = 0; o < 16; ++o) ph[o] += pw[o*256 + c] * xv;
    }
    if (half == 0) {
      #pragma unroll
      for (int o = 0; o < 16; ++o) phs[hwl*18 + o] = ph[o];
      phs[hwl*18 + 16] = sacc;
    }
    __syncthreads();
    if (half == 1) {
      #pragma unroll
      for (int o = 0; o < 16; ++o) phs[hwl*18 + o] += ph[o];
      s_raw[b*1024 + hw] = phs[hwl*18 + 16] + sacc;
    }
    __syncthreads();
    float csacc = 0.f;
    #pragma unroll
    for (int i = 0; i < 8; ++i) {
      int j = i*256 + t;
      int o = j >> 7, hl = j & 127;
      float val = fmaxf(phs[hl*18 + o] + pb[o], 0.f);
      bf16_t bv16 = (bf16_t)val;
      atomicMax(&fmu[o], __float_as_uint((float)bv16));
      fB [b*16384 + o*1024 + role*128 + hl] = bv16;            // m-major (raw)
      fBT[b*16384 + (role*128 + hl)*16 + o] = bv16;            // q-major
      csacc += (float)bv16;
    }
    if (half == 0) phs[hwl*18 + 17] = csacc;
    __syncthreads();
    if (half == 1) {
      float cs = phs[hwl*18 + 17] + csacc;
      csum[b*1024 + hw] = cs;
      atomicMax(cmu, __float_as_uint(cs));
    }
    if (t < 16) fmaxp[b*128 + role*16 + t] = __uint_as_float(fmu[t]);
    __syncthreads();
    if (t == 0) cmaxp[b*8 + role] = __uint_as_float(cmu[0]);
    // xsum partial for this (b, role): L2-hot re-read, thread owns channel c = t
    {
      const f32x4* xr = (const f32x4*)(xb + t*1024 + role*128);
      float s4 = 0.f;
      #pragma unroll
      for (int j = 0; j < 32; ++j) { f32x4 v = xr[j]; s4 += v[0] + v[1] + v[2] + v[3]; }
      xsump[(b*8 + role)*256 + t] = s4;
    }
    return;
  }
  if (bid < 464) {                       // ---- E1 = emb @ gc1_w ----
    int n = bid - 444;
    float* er = (float*)sp;
    for (int i = t; i < 300; i += 256) er[i] = emb[n*300 + i];
    __syncthreads();
    float acc = 0.f;
    for (int d = 0; d < 300; ++d) acc += er[d] * gc1_w[d*256 + t];
    E1[n*256 + t] = acc;
    return;
  }
  if (bid < 765) {                       // ---- WG1 rows / bg1 ----
    int d0 = bid - 464;                  // 0..300
    float* er = (float*)sp;
    if (d0 < 300) { for (int i = t; i < 300; i += 256) er[i] = wo[d0*300 + i]; }
    else          { for (int i = t; i < 300; i += 256) er[i] = bo[i]; }
    __syncthreads();
    float acc = 0.f;
    for (int e = 0; e < 300; ++e) acc += er[e] * gc1_w[e*256 + t];
    if (d0 < 300) WG1[d0*256 + t] = acc; else bg1[t] = acc;
    return;
  }
  {                                      // ---- k_xt: raw-reshape transpose ----
    int id = bid - 765;                  // 0..1023
    int bb = id >> 6, tile = id & 63;
    int q0 = (tile >> 2) * 64, c0 = (tile & 3) * 64;
    bf16_t* tl = (bf16_t*)sp;            // [64][74]
    const float* xbb = x + bb*262144;
    #pragma unroll
    for (int k = 0; k < 16; ++k) {
      int idx = k*256 + t, qi = idx >> 6, ci = idx & 63;
      tl[ci*74 + qi] = (bf16_t)xbb[(q0 + qi)*256 + c0 + ci];
    }
    __syncthreads();
    #pragma unroll
    for (int k = 0; k < 16; ++k) {
      int idx = k*256 + t, ci = idx >> 6, qi = idx & 63;
      xT[bb*262144 + (c0 + ci)*1024 + q0 + qi] = tl[ci*74 + qi];
    }
    return;
  }
}

// =================== LAUNCH B: k_mid1 (18 blocks x 512) ===================
// block 0 : att softmax -> wsum -> n1
// block 1 : adjn/rsA from adj; AE1 = adjn @ E1
// blocks 2-17: dgm for b = blockIdx.x-2, plus fmax/cmax partial reduction
__global__ __launch_bounds__(512) void k_mid1(
    const float* adj, const float* qkv, const float* E1,
    const float* glob_w, const float* xsump, const float* s_raw,
    const float* fmaxp, const float* cmaxp,
    float* n1g, float* adjng, float* rsAg, float* AE1g,
    float* dgd, float* mcol, float* fmaxb, float* cmaxb) {
  __shared__ __align__(16) float sp[12480];
  int t = threadIdx.x;
  if (blockIdx.x == 0) {                 // ---- attention -> n1 ----
    float* A  = sp;            // 6000 q
    float* Bs = A + 6000;      // 6000 k
    float* att  = Bs + 6000;   // 400
    float* wsum = att + 400;   // 20
    for (int i = t; i < 6000; i += 512) { A[i] = qkv[i]; Bs[i] = qkv[6000 + i]; }
    __syncthreads();
    if (t < 400) {
      int i = t / 20, j = t % 20;
      float acc = 0.f;
      for (int d = 0; d < 300; ++d) acc += A[i*300 + d] * Bs[j*300 + d];
      att[t] = acc * 0.05773502691896258f;  // 1/sqrt(300)
    }
    __syncthreads();
    if (t < 20) {
      float m = -1e30f;
      for (int j = 0; j < 20; ++j) m = fmaxf(m, att[t*20 + j]);
      float s = 0.f;
      for (int j = 0; j < 20; ++j) { float e = __expf(att[t*20 + j] - m); att[t*20 + j] = e; s += e; }
      float inv = 1.f / s;
      for (int j = 0; j < 20; ++j) att[t*20 + j] *= inv;
    }
    __syncthreads();
    if (t < 20) {
      float s = 0.f;
      for (int i = 0; i < 20; ++i) s += att[i*20 + t];
      wsum[t] = s * 0.05f;
    }
    __syncthreads();
    if (t < 300) {
      const float* v = qkv + 12000;
      float acc = 0.f;
      for (int j = 0; j < 20; ++j) acc += wsum[j] * v[j*300 + t];
      n1g[t] = acc;
    }
    return;
  }
  if (blockIdx.x == 1) {                 // ---- adjn / rsA / AE1 ----
    float* drt = sp;           // 20
    float* an  = sp + 32;      // 400
    if (t < 20) {
      float s = 1.f;
      for (int j = 0; j < 20; ++j) s += adj[t*20 + j];
      drt[t] = rsqrtf(s);
    }
    __syncthreads();
    if (t < 400) {
      int i = t / 20, j = t % 20;
      float a = adj[t] + (i == j ? 1.f : 0.f);
      float v = drt[i] * a * drt[j];
      an[t] = v;
      adjng[t] = v;
    }
    __syncthreads();
    if (t < 20) {
      float s = 0.f;
      for (int m = 0; m < 20; ++m) s += an[t*20 + m];
      rsAg[t] = s;
    }
    if (t < 256) {
      float e[20];
      #pragma unroll
      for (int m = 0; m < 20; ++m) e[m] = E1[m*256 + t];
      for (int n = 0; n < 20; ++n) {
        float acc = 0.f;
        #pragma unroll
        for (int m = 0; m < 20; ++m) acc += an[n*20 + m] * e[m];
        AE1g[n*256 + t] = acc;
      }
    }
    return;
  }
  // ---- dgm + fmax/cmax reduce, b = blockIdx.x-2 ----
  int b = blockIdx.x - 2;
  float* xm = sp;            // 256
  float* redm = xm + 256;    // 8
  float* reds = redm + 8;    // 8
  if (t < 256) {
    float s = 0.f;
    #pragma unroll
    for (int r = 0; r < 8; ++r) s += xsump[(b*8 + r)*256 + t];
    xm[t] = s * (1.f / 1024.f);
  }
  if (t >= 256 && t < 272) {
    int m = t - 256; float fm = 0.f;
    for (int r = 0; r < 8; ++r) fm = fmaxf(fm, fmaxp[b*128 + r*16 + m]);
    fmaxb[b*16 + m] = fm;
  }
  if (t == 272) {
    float cm = 0.f;
    for (int r = 0; r < 8; ++r) cm = fmaxf(cm, cmaxp[b*8 + r]);
    cmaxb[b] = cm;
  }
  __syncthreads();
  if (t < 16) {
    float g = 0.f;
    for (int c = 0; c < 256; ++c) g += glob_w[t*256 + c] * xm[c];
    dgd[b*16 + t] = 0.5f * tanhf(0.5f * g);   // sigmoid(g) - 0.5
  }
  float v0 = s_raw[b*1024 + t], v1 = s_raw[b*1024 + 512 + t];
  float m = fmaxf(v0, v1);
  #pragma unroll
  for (int off = 32; off; off >>= 1) m = fmaxf(m, __shfl_xor(m, off, 64));
  int wv = t >> 6, ll = t & 63;
  if (ll == 0) redm[wv] = m;
  __syncthreads();
  float bm = redm[0];
  #pragma unroll
  for (int i = 1; i < 8; ++i) bm = fmaxf(bm, redm[i]);
  float e0 = __expf(v0 - bm), e1 = __expf(v1 - bm);
  float s2 = e0 + e1;
  #pragma unroll
  for (int off = 32; off; off >>= 1) s2 += __shfl_xor(s2, off, 64);
  if (ll == 0) reds[wv] = s2;
  __syncthreads();
  float tot = 0.f;
  #pragma unroll
  for (int i = 0; i < 8; ++i) tot += reds[i];
  float inv = 1.f / tot;
  mcol[b*1024 + t]       = e0 * inv;
  mcol[b*1024 + 512 + t] = e1 * inv;
}

// =================== LAUNCH C: k_gu (8 blocks) ===================
// Each block: w1 full (redundant); g1 full; h2/g2/rg for its 32-col slice;
// upart[block][o] = partial u over its k-slice.
__global__ __launch_bounds__(256) void k_gu(const float* n1g, const float* WG1,
    const float* bg1, const float* AE1g, const float* rsAg, const float* adjng,
    const float* gc2_w, const float* final_w, float* upart) {
  __shared__ float n1s[304], adjns[400], rsAs[32], w1s[256], h2s[640], rgs[32];
  __shared__ float g1s[5120];
  int t = threadIdx.x, c0 = blockIdx.x * 32;
  for (int i = t; i < 300; i += 256) n1s[i] = n1g[i];
  for (int i = t; i < 400; i += 256) adjns[i] = adjng[i];
  if (t < 20) rsAs[t] = rsAg[t];
  __syncthreads();
  {  // w1 = bg1 + n1 @ WG1  (full 256)
    float acc = bg1[t];
    for (int d = 0; d < 300; ++d) acc += n1s[d] * WG1[d*256 + t];
    w1s[t] = acc;
  }
  __syncthreads();
  for (int i = t; i < 5120; i += 256) {
    int n = i >> 8;
    g1s[i] = fmaxf(AE1g[i] + rsAs[n] * w1s[i & 255], 0.f);
  }
  __syncthreads();
  int cl = t & 31, ng = t >> 5;
  float a0 = 0.f, a1 = 0.f, a2 = 0.f;
  for (int d = 0; d < 256; ++d) {
    float wv = gc2_w[d*256 + c0 + cl];
    a0 += g1s[ng*256 + d] * wv;
    a1 += g1s[(ng + 8)*256 + d] * wv;
    if (ng < 4) a2 += g1s[(ng + 16)*256 + d] * wv;
  }
  h2s[ng*32 + cl] = a0;
  h2s[(ng + 8)*32 + cl] = a1;
  if (ng < 4) h2s[(ng + 16)*32 + cl] = a2;
  __syncthreads();
  if (t < 32) {
    float rga = 0.f;
    for (int n = 0; n < 20; ++n) {
      float acc = 0.f;
      #pragma unroll
      for (int m = 0; m < 20; ++m) acc += adjns[n*20 + m] * h2s[m*32 + t];
      rga += fmaxf(acc, 0.f);
    }
    rgs[t] = rga;
  }
  __syncthreads();
  {  // upart over this block's k-slice
    float acc = 0.f;
    const float* fw = final_w + t*512 + 256 + c0;
    #pragma unroll
    for (int kk = 0; kk < 32; ++kk) acc += fw[kk] * rgs[kk];
    upart[blockIdx.x*256 + t] = acc;
  }
}

// =================== LAUNCH D: k_main ===================
// S[p,q] = sum_m e'[p,m] f[m,q] (MFMA) + 0.5*a[p]*c[q]; E=exp(S-Mb); rowsum;
// S2u += E @ x_r; T = x_r - S2u/rs; out = relu(M@T^T + mcol*u + x).
// p-tile 32, grid (32,16) = 512 blocks (2/CU), XCD remap (2 batches/XCD).
// 2 st per barrier (16 barriers); bv/a0 prefetched one super-iter ahead.
__global__ __launch_bounds__(256) void k_main(const float* x, const bf16_t* fB,
    const bf16_t* fBT, const bf16_t* xT, const bf16_t* M16, const float* fmaxb,
    const float* mcol, const float* upart, const float* dgd, const float* csum,
    const float* cmaxb, float* out) {
  int flat = blockIdx.y * 32 + blockIdx.x;
  int b  = (flat & 7) * 2 + ((flat >> 3) >> 5);   // bijective XCD remap
  int p0 = ((flat >> 3) & 31) * 32;
  int t = threadIdx.x, w = t >> 6, l = t & 63, lr = l & 15, quad = l >> 4;
  int qh = w >> 1, ph = w & 1;
  __shared__ __align__(16) char smem[16896];       // union: {PT dbuf(2x2 tiles) | e_s} / T_ls
  bf16_t* PT0  = (bf16_t*)smem;                    // 2 buf x 2 tiles x [32][40]
  bf16_t* e_s  = (bf16_t*)(smem + 10240);          // [32][40] (m>=16 zero)
  bf16_t* T_ls = (bf16_t*)smem;                    // [32][264] phase 2
  __shared__ float Mb_s[32], fmax_s[16], u_s[256], rsinv_s[32], dgd_s[16];
  __shared__ float c_s[1024], ha_s[32], rs_s[2][32];
  const float*  xb   = x   + b*262144;
  const bf16_t* fBb  = fB  + b*16384;
  const bf16_t* fBTb = fBT + b*16384;
  const bf16_t* xTb  = xT  + b*262144;
  for (int i = t; i < 1280; i += 256) e_s[i] = (bf16_t)0.f;
  {
    float us = 0.f;
    #pragma unroll
    for (int j = 0; j < 8; ++j) us += upart[j*256 + t];
    u_s[t] = us;
  }
  for (int i = t; i < 1024; i += 256) c_s[i] = csum[b*1024 + i];
  if (t < 16) { fmax_s[t] = fmaxb[b*16 + t]; dgd_s[t] = dgd[b*16 + t]; }
  __syncthreads();
  for (int i = t; i < 512; i += 256) {       // e'[p,m] = x_phi * (sig(g[m])-0.5)
    int p = i >> 4, m = i & 15;
    e_s[p*40 + m] = (bf16_t)((float)fBb[p0*16 + i] * dgd_s[m]);
  }
  __syncthreads();
  if (t < 32) {
    float a = 0.f;
    #pragma unroll
    for (int m = 0; m < 16; ++m) a += (float)fBb[(p0 + t)*16 + m];
    float ha = 0.5f * a;
    ha_s[t] = ha;
    float mb = ha * cmaxb[b];
    #pragma unroll
    for (int m = 0; m < 16; ++m) mb += fmaxf((float)e_s[t*40 + m], 0.f) * fmax_s[m];
    Mb_s[t] = mb;  // exact upper bound on row max of S
  }
  __syncthreads();
  bf16x8 be = *(const bf16x8*)(e_s + (ph*16 + lr)*40 + quad*8);
  float mb_lane = Mb_s[ph*16 + lr];
  float ha_lane = ha_s[ph*16 + lr];
  float rs = 0.f;
  f32x4 acc[2][4];  // S2u[p = pf*16+quad*4+r][c = w*64+cf*16+lr]
  #pragma unroll
  for (int i = 0; i < 2; ++i)
    #pragma unroll
    for (int j = 0; j < 4; ++j) acc[i][j] = (f32x4){0.f, 0.f, 0.f, 0.f};
  bf16x8 zer;
  #pragma unroll
  for (int j = 0; j < 8; ++j) zer[j] = (bf16_t)0.f;
  bf16x8 a0[2], a0n[2];
  a0[0] = a0[1] = a0n[0] = a0n[1] = zer;
  if (quad < 2) {
    a0[0] = *(const bf16x8*)(fBTb + (qh*16 + lr)*16 + quad*8);
    a0[1] = *(const bf16x8*)(fBTb + (32 + qh*16 + lr)*16 + quad*8);
  }
  const bf16_t* xrow = xTb + (w*64 + lr)*1024 + quad*8;
  bf16x8 bv[2][4], bvn[2][4];
  #pragma unroll
  for (int k = 0; k < 2; ++k)
    #pragma unroll
    for (int cf = 0; cf < 4; ++cf)
      bv[k][cf] = *(const bf16x8*)(xrow + cf*16384 + k*32);
  int cur = 0;
  for (int u2 = 0; u2 < 16; ++u2) {
    f32x4 z = {0.f, 0.f, 0.f, 0.f};
    f32x4 s0 = MFMA(a0[0], be, z);   // D[q=(2u2)*32+qh*16+quad*4+r][p=ph*16+lr]
    f32x4 s1 = MFMA(a0[1], be, z);   // st 2u2+1
    if (u2 < 15) {                   // prefetch next super-iter (lands during barrier)
      if (quad < 2) {
        a0n[0] = *(const bf16x8*)(fBTb + ((u2*2 + 2)*32 + qh*16 + lr)*16 + quad*8);
        a0n[1] = *(const bf16x8*)(fBTb + ((u2*2 + 3)*32 + qh*16 + lr)*16 + quad*8);
      }
      #pragma unroll
      for (int k = 0; k < 2; ++k)
        #pragma unroll
        for (int cf = 0; cf < 4; ++cf)
          bvn[k][cf] = *(const bf16x8*)(xrow + cf*16384 + (u2*2 + 2 + k)*32);
    }
    bf16_t* PTc = PT0 + cur*2560;
    bf16x4 pv0, pv1;
    #pragma unroll
    for (int r = 0; r < 4; ++r) {
      float S0 = s0[r] + ha_lane * c_s[(u2*2)*32 + qh*16 + quad*4 + r];
      float E0 = __expf(S0 - mb_lane);
      rs += E0; pv0[r] = (bf16_t)E0;
      float S1 = s1[r] + ha_lane * c_s[(u2*2 + 1)*32 + qh*16 + quad*4 + r];
      float E1v = __expf(S1 - mb_lane);
      rs += E1v; pv1[r] = (bf16_t)E1v;
    }
    *(bf16x4*)(PTc + (ph*16 + lr)*40 + qh*16 + quad*4)        = pv0;
    *(bf16x4*)(PTc + 1280 + (ph*16 + lr)*40 + qh*16 + quad*4) = pv1;
    __syncthreads();
    #pragma unroll
    for (int k = 0; k < 2; ++k) {
      bf16x8 ap0 = *(const bf16x8*)(PTc + k*1280 + lr*40 + quad*8);
      bf16x8 ap1 = *(const bf16x8*)(PTc + k*1280 + (16 + lr)*40 + quad*8);
      #pragma unroll
      for (int cf = 0; cf < 4; ++cf) {
        acc[0][cf] = MFMA(ap0, bv[k][cf], acc[0][cf]);
        acc[1][cf] = MFMA(ap1, bv[k][cf], acc[1][cf]);
      }
    }
    if (u2 < 15) {
      #pragma unroll
      for (int k = 0; k < 2; ++k) {
        a0[k] = a0n[k];
        #pragma unroll
        for (int cf = 0; cf < 4; ++cf) bv[k][cf] = bvn[k][cf];
      }
    }
    cur ^= 1;
  }
  rs += __shfl_xor(rs, 16, 64);
  rs += __shfl_xor(rs, 32, 64);          // qh-half rowsum for p = ph*16+lr
  if (l < 16) rs_s[qh][ph*16 + lr] = rs;
  __syncthreads();   // rs staged; all PT/e_s reads drained -> T_ls may overwrite
  if (t < 32) rsinv_s[t] = 1.f / fmaxf(rs_s[0][t] + rs_s[1][t], 1e-30f);
  __syncthreads();
  #pragma unroll
  for (int pf = 0; pf < 2; ++pf)
    #pragma unroll
    for (int cf = 0; cf < 4; ++cf)
      #pragma unroll
      for (int r = 0; r < 4; ++r) {
        int p = pf*16 + quad*4 + r;
        int c = w*64 + cf*16 + lr;
        float tv = xb[(p0 + p)*256 + c] - acc[pf][cf][r] * rsinv_s[p];
        T_ls[p*264 + c] = (bf16_t)tv;    // spiral[p][c]
      }
  __syncthreads();
  f32x4 acc2[4][2];  // D2[o = w*64+of*16+quad*4+r][p = pf*16+lr]
  #pragma unroll
  for (int i = 0; i < 4; ++i)
    #pragma unroll
    for (int j = 0; j < 2; ++j) acc2[i][j] = (f32x4){0.f, 0.f, 0.f, 0.f};
  for (int c0 = 0; c0 < 256; c0 += 32) {
    bf16x8 am[4], bt[2];
    #pragma unroll
    for (int of = 0; of < 4; ++of)
      am[of] = *(const bf16x8*)(M16 + (w*64 + of*16 + lr)*256 + c0 + quad*8);
    #pragma unroll
    for (int pf = 0; pf < 2; ++pf)
      bt[pf] = *(const bf16x8*)(T_ls + (pf*16 + lr)*264 + c0 + quad*8);
    #pragma unroll
    for (int of = 0; of < 4; ++of)
      #pragma unroll
      for (int pf = 0; pf < 2; ++pf) acc2[of][pf] = MFMA(am[of], bt[pf], acc2[of][pf]);
  }
  float* outb = out + b*262144;
  #pragma unroll
  for (int of = 0; of < 4; ++of)
    #pragma unroll
    for (int pf = 0; pf < 2; ++pf)
      #pragma unroll
      for (int r = 0; r < 4; ++r) {
        int o = w*64 + of*16 + quad*4 + r;
        int pg = p0 + pf*16 + lr;
        float v = acc2[of][pf][r] + mcol[b*1024 + pg] * u_s[o] + xb[o*1024 + pg];
        outb[o*1024 + pg] = fmaxf(v, 0.f);
      }
}

// ---------------- launch ----------------

extern "C" void kernel_launch(void* const* d_in, const int* in_sizes, int n_in,
                              void* d_out, int out_size, void* d_ws, size_t ws_size,
                              hipStream_t stream) {
  (void)in_sizes; (void)n_in; (void)out_size; (void)ws_size;
  const float* x       = (const float*)d_in[0];
  const float* emb     = (const float*)d_in[1];
  const float* adj     = (const float*)d_in[2];
  const float* wq      = (const float*)d_in[3];
  const float* bq      = (const float*)d_in[4];
  const float* wk      = (const float*)d_in[5];
  const float* bk      = (const float*)d_in[6];
  const float* wv      = (const float*)d_in[7];
  const float* bv      = (const float*)d_in[8];
  const float* wo      = (const float*)d_in[9];
  const float* bo      = (const float*)d_in[10];
  const float* phi_w   = (const float*)d_in[11];
  const float* phi_b   = (const float*)d_in[12];
  const float* glob_w  = (const float*)d_in[13];
  const float* gc1_w   = (const float*)d_in[14];
  const float* gc2_w   = (const float*)d_in[15];
  const float* gw_w    = (const float*)d_in[16];
  const float* s2l_w   = (const float*)d_in[17];
  const float* final_w = (const float*)d_in[19];
  float* out = (float*)d_out;

  float* W = (float*)d_ws;
  float* qkv   = W + 0;        // 18000 -> 18048
  float* xsump = W + 18048;    // 32768 -> 50816
  float* s_raw = W + 50816;    // 16384 -> 67200
  float* mcol  = W + 67200;    // 16384 -> 83584
  float* fmaxb = W + 83584;    // 256   -> 83840
  float* dgd   = W + 83840;    // 256   -> 84096
  float* csum  = W + 84096;    // 16384 -> 100480
  float* cmaxb = W + 100480;   // 64    -> 100544
  float* fmaxp = W + 100544;   // 2048  -> 102592
  float* cmaxp = W + 102592;   // 128   -> 102720
  float* E1    = W + 102720;   // 5120  -> 107840
  float* WG1   = W + 107840;   // 76800 -> 184640
  float* bg1   = W + 184640;   // 256   -> 184896
  float* n1    = W + 184896;   // 320   -> 185216
  float* adjn  = W + 185216;   // 448   -> 185664
  float* rsA   = W + 185664;   // 64    -> 185728
  float* AE1   = W + 185728;   // 5120  -> 190848
  float* upart = W + 190848;   // 2048  -> 192896 floats (771584 B)
  bf16_t* M16 = (bf16_t*)((char*)d_ws + 786432);   // 128 KB
  bf16_t* fB  = (bf16_t*)((char*)d_ws + 917504);   // 512 KB (m-major raw)
  bf16_t* fBT = (bf16_t*)((char*)d_ws + 1441792);  // 512 KB (q-major)
  bf16_t* xT  = (bf16_t*)((char*)d_ws + 1966080);  // 8 MB  (x transposed bf16)
  // total ws usage ~10.4 MB

  k_front<<<1789, 256, 0, stream>>>(final_w, gw_w, emb, wq, bq, wk, bk, wv, bv, x,
                                    phi_w, phi_b, s2l_w, gc1_w, wo, bo,
                                    M16, qkv, fB, fBT, s_raw, xsump, csum,
                                    fmaxp, cmaxp, xT, E1, WG1, bg1);
  k_mid1<<<18, 512, 0, stream>>>(adj, qkv, E1, glob_w, xsump, s_raw,
                                 fmaxp, cmaxp,
                                 n1, adjn, rsA, AE1, dgd, mcol, fmaxb, cmaxb);
  k_gu<<<8, 256, 0, stream>>>(n1, WG1, bg1, AE1, rsA, adjn, gc2_w, final_w, upart);
  k_main<<<dim3(32, 16), 256, 0, stream>>>(x, fB, fBT, xT, M16, fmaxb, mcol, upart,
                                           dgd, csum, cmaxb, out);
}

// Round 6
// 232.430 us; speedup vs baseline: 1.2834x; 1.0229x over previous
//
#include <hip/hip_runtime.h>
#include <hip/hip_bf16.h>

// Inputs/outputs are FLOAT32 (reference dtype). bf16 used only internally for MFMA.
typedef __bf16 bf16_t;
typedef bf16_t bf16x8 __attribute__((ext_vector_type(8)));
typedef bf16_t bf16x4 __attribute__((ext_vector_type(4)));
typedef float  f32x4  __attribute__((ext_vector_type(4)));

#define MFMA(a,b,c) __builtin_amdgcn_mfma_f32_16x16x32_bf16((a),(b),(c),0,0,0)

// =================== LAUNCH A: k_front (1789 blocks) ===================
// roles by blockIdx.x:
//   [0,256)     : M = final_w[:, :256] @ gw_w  (bf16)
//   [256,316)   : qkv = emb @ {wq,wk,wv} + bias
//   [316,444)   : phis (8 roles x 16 b): fB, fBT, s_raw, csum, fmax/cmax, xsump
//   [444,464)   : E1 = emb @ gc1_w  [20][256]
//   [464,765)   : WG1 = wo @ gc1_w [300][256]; row 300 = bg1 = bo @ gc1_w
//   [765,1789)  : xT transpose: raw [1024q][256c] fp32 -> xT [256c][1024q] bf16
__global__ __launch_bounds__(256) void k_front(
    const float* final_w, const float* gw_w, const float* emb,
    const float* wq, const float* bq, const float* wk, const float* bk,
    const float* wv, const float* bvv, const float* x,
    const float* phi_w, const float* phi_b, const float* s2l_w,
    const float* gc1_w, const float* wo, const float* bo,
    bf16_t* M16, float* qkv, bf16_t* fB, bf16_t* fBT, float* s_raw,
    float* xsump, float* csum, float* fmaxp, float* cmaxp, bf16_t* xT,
    float* E1, float* WG1, float* bg1) {
  __shared__ __align__(16) char sp[27648];
  int bid = blockIdx.x, t = threadIdx.x;
  if (bid < 256) {                       // ---- k_M ----
    float* fw = (float*)sp;
    int o = bid, c = t;
    fw[c] = final_w[o*512 + c];
    __syncthreads();
    float acc = 0.f;
    for (int k = 0; k < 256; ++k) acc += fw[k] * gw_w[k*256 + c];
    M16[o*256 + c] = (bf16_t)acc;
    return;
  }
  if (bid < 316) {                       // ---- k_qkv ----
    int id = bid - 256;
    int mat = id / 20, row = id % 20;
    const float* W  = mat == 0 ? wq : (mat == 1 ? wk : wv);
    const float* Bb = mat == 0 ? bq : (mat == 1 ? bk : bvv);
    float* er = (float*)sp;
    for (int i = t; i < 300; i += 256) er[i] = emb[row*300 + i];
    __syncthreads();
    for (int o = t; o < 300; o += 256) {
      float acc = Bb[o];
      for (int d = 0; d < 300; ++d) acc += er[d] * W[d*300 + o];
      qkv[(mat*20 + row)*300 + o] = acc;
    }
    return;
  }
  if (bid < 444) {                       // ---- k_phis ----
    int id = bid - 316;
    int b = id >> 3, role = id & 7;
    const float* xb = x + b*262144;
    float* pw = (float*)sp;              // 4096
    float* wi = pw + 4096;               // 256
    float* pb = wi + 256;                // 16
    float* phs = pb + 16;                // [128][18]
    unsigned* fmu = (unsigned*)(phs + 2304);  // 16
    unsigned* cmu = fmu + 16;            // 1
    for (int i = t; i < 4096; i += 256) pw[i] = phi_w[i];
    wi[t] = s2l_w[t];
    if (t < 16) { pb[t] = phi_b[t]; fmu[t] = 0u; }
    if (t == 0) cmu[0] = 0u;
    __syncthreads();
    int hwl = t & 127, half = t >> 7;
    int hw = role*128 + hwl;
    float ph[16];
    #pragma unroll
    for (int o = 0; o < 16; ++o) ph[o] = 0.f;
    float sacc = 0.f;
    for (int ci = 0; ci < 128; ++ci) {
      int c = half*128 + ci;
      float xv = xb[c*1024 + hw];
      sacc += wi[c] * xv;
      #pragma unroll
      for (int o = 0; o < 16; ++o) ph[o] += pw[o*256 + c] * xv;
    }
    if (half == 0) {
      #pragma unroll
      for (int o = 0; o < 16; ++o) phs[hwl*18 + o] = ph[o];
      phs[hwl*18 + 16] = sacc;
    }
    __syncthreads();
    if (half == 1) {
      #pragma unroll
      for (int o = 0; o < 16; ++o) phs[hwl*18 + o] += ph[o];
      s_raw[b*1024 + hw] = phs[hwl*18 + 16] + sacc;
    }
    __syncthreads();
    float csacc = 0.f;
    #pragma unroll
    for (int i = 0; i < 8; ++i) {
      int j = i*256 + t;
      int o = j >> 7, hl = j & 127;
      float val = fmaxf(phs[hl*18 + o] + pb[o], 0.f);
      bf16_t bv16 = (bf16_t)val;
      atomicMax(&fmu[o], __float_as_uint((float)bv16));
      fB [b*16384 + o*1024 + role*128 + hl] = bv16;            // m-major (raw)
      fBT[b*16384 + (role*128 + hl)*16 + o] = bv16;            // q-major
      csacc += (float)bv16;
    }
    if (half == 0) phs[hwl*18 + 17] = csacc;
    __syncthreads();
    if (half == 1) {
      float cs = phs[hwl*18 + 17] + csacc;
      csum[b*1024 + hw] = cs;
      atomicMax(cmu, __float_as_uint(cs));
    }
    if (t < 16) fmaxp[b*128 + role*16 + t] = __uint_as_float(fmu[t]);
    __syncthreads();
    if (t == 0) cmaxp[b*8 + role] = __uint_as_float(cmu[0]);
    // xsum partial for this (b, role): L2-hot re-read, thread owns channel c = t
    {
      const f32x4* xr = (const f32x4*)(xb + t*1024 + role*128);
      float s4 = 0.f;
      #pragma unroll
      for (int j = 0; j < 32; ++j) { f32x4 v = xr[j]; s4 += v[0] + v[1] + v[2] + v[3]; }
      xsump[(b*8 + role)*256 + t] = s4;
    }
    return;
  }
  if (bid < 464) {                       // ---- E1 = emb @ gc1_w ----
    int n = bid - 444;
    float* er = (float*)sp;
    for (int i = t; i < 300; i += 256) er[i] = emb[n*300 + i];
    __syncthreads();
    float acc = 0.f;
    for (int d = 0; d < 300; ++d) acc += er[d] * gc1_w[d*256 + t];
    E1[n*256 + t] = acc;
    return;
  }
  if (bid < 765) {                       // ---- WG1 rows / bg1 ----
    int d0 = bid - 464;                  // 0..300
    float* er = (float*)sp;
    if (d0 < 300) { for (int i = t; i < 300; i += 256) er[i] = wo[d0*300 + i]; }
    else          { for (int i = t; i < 300; i += 256) er[i] = bo[i]; }
    __syncthreads();
    float acc = 0.f;
    for (int e = 0; e < 300; ++e) acc += er[e] * gc1_w[e*256 + t];
    if (d0 < 300) WG1[d0*256 + t] = acc; else bg1[t] = acc;
    return;
  }
  {                                      // ---- k_xt: raw-reshape transpose ----
    int id = bid - 765;                  // 0..1023
    int bb = id >> 6, tile = id & 63;
    int q0 = (tile >> 2) * 64, c0 = (tile & 3) * 64;
    bf16_t* tl = (bf16_t*)sp;            // [64][74]
    const float* xbb = x + bb*262144;
    #pragma unroll
    for (int k = 0; k < 16; ++k) {
      int idx = k*256 + t, qi = idx >> 6, ci = idx & 63;
      tl[ci*74 + qi] = (bf16_t)xbb[(q0 + qi)*256 + c0 + ci];
    }
    __syncthreads();
    #pragma unroll
    for (int k = 0; k < 16; ++k) {
      int idx = k*256 + t, ci = idx >> 6, qi = idx & 63;
      xT[bb*262144 + (c0 + ci)*1024 + q0 + qi] = tl[ci*74 + qi];
    }
    return;
  }
}

// =================== LAUNCH B: k_mid1 (18 blocks x 512) ===================
// block 0 : att softmax -> wsum -> n1
// block 1 : adjn/rsA from adj; AE1 = adjn @ E1
// blocks 2-17: dgm for b = blockIdx.x-2, plus fmax/cmax partial reduction
__global__ __launch_bounds__(512) void k_mid1(
    const float* adj, const float* qkv, const float* E1,
    const float* glob_w, const float* xsump, const float* s_raw,
    const float* fmaxp, const float* cmaxp,
    float* n1g, float* adjng, float* rsAg, float* AE1g,
    float* dgd, float* mcol, float* fmaxb, float* cmaxb) {
  __shared__ __align__(16) float sp[12480];
  int t = threadIdx.x;
  if (blockIdx.x == 0) {                 // ---- attention -> n1 ----
    float* A  = sp;            // 6000 q
    float* Bs = A + 6000;      // 6000 k
    float* att  = Bs + 6000;   // 400
    float* wsum = att + 400;   // 20
    for (int i = t; i < 6000; i += 512) { A[i] = qkv[i]; Bs[i] = qkv[6000 + i]; }
    __syncthreads();
    if (t < 400) {
      int i = t / 20, j = t % 20;
      float acc = 0.f;
      for (int d = 0; d < 300; ++d) acc += A[i*300 + d] * Bs[j*300 + d];
      att[t] = acc * 0.05773502691896258f;  // 1/sqrt(300)
    }
    __syncthreads();
    if (t < 20) {
      float m = -1e30f;
      for (int j = 0; j < 20; ++j) m = fmaxf(m, att[t*20 + j]);
      float s = 0.f;
      for (int j = 0; j < 20; ++j) { float e = __expf(att[t*20 + j] - m); att[t*20 + j] = e; s += e; }
      float inv = 1.f / s;
      for (int j = 0; j < 20; ++j) att[t*20 + j] *= inv;
    }
    __syncthreads();
    if (t < 20) {
      float s = 0.f;
      for (int i = 0; i < 20; ++i) s += att[i*20 + t];
      wsum[t] = s * 0.05f;
    }
    __syncthreads();
    if (t < 300) {
      const float* v = qkv + 12000;
      float acc = 0.f;
      for (int j = 0; j < 20; ++j) acc += wsum[j] * v[j*300 + t];
      n1g[t] = acc;
    }
    return;
  }
  if (blockIdx.x == 1) {                 // ---- adjn / rsA / AE1 ----
    float* drt = sp;           // 20
    float* an  = sp + 32;      // 400
    if (t < 20) {
      float s = 1.f;
      for (int j = 0; j < 20; ++j) s += adj[t*20 + j];
      drt[t] = rsqrtf(s);
    }
    __syncthreads();
    if (t < 400) {
      int i = t / 20, j = t % 20;
      float a = adj[t] + (i == j ? 1.f : 0.f);
      float v = drt[i] * a * drt[j];
      an[t] = v;
      adjng[t] = v;
    }
    __syncthreads();
    if (t < 20) {
      float s = 0.f;
      for (int m = 0; m < 20; ++m) s += an[t*20 + m];
      rsAg[t] = s;
    }
    if (t < 256) {
      float e[20];
      #pragma unroll
      for (int m = 0; m < 20; ++m) e[m] = E1[m*256 + t];
      for (int n = 0; n < 20; ++n) {
        float acc = 0.f;
        #pragma unroll
        for (int m = 0; m < 20; ++m) acc += an[n*20 + m] * e[m];
        AE1g[n*256 + t] = acc;
      }
    }
    return;
  }
  // ---- dgm + fmax/cmax reduce, b = blockIdx.x-2 ----
  int b = blockIdx.x - 2;
  float* xm = sp;            // 256
  float* redm = xm + 256;    // 8
  float* reds = redm + 8;    // 8
  if (t < 256) {
    float s = 0.f;
    #pragma unroll
    for (int r = 0; r < 8; ++r) s += xsump[(b*8 + r)*256 + t];
    xm[t] = s * (1.f / 1024.f);
  }
  if (t >= 256 && t < 272) {
    int m = t - 256; float fm = 0.f;
    for (int r = 0; r < 8; ++r) fm = fmaxf(fm, fmaxp[b*128 + r*16 + m]);
    fmaxb[b*16 + m] = fm;
  }
  if (t == 272) {
    float cm = 0.f;
    for (int r = 0; r < 8; ++r) cm = fmaxf(cm, cmaxp[b*8 + r]);
    cmaxb[b] = cm;
  }
  __syncthreads();
  if (t < 16) {
    float g = 0.f;
    for (int c = 0; c < 256; ++c) g += glob_w[t*256 + c] * xm[c];
    dgd[b*16 + t] = 0.5f * tanhf(0.5f * g);   // sigmoid(g) - 0.5
  }
  float v0 = s_raw[b*1024 + t], v1 = s_raw[b*1024 + 512 + t];
  float m = fmaxf(v0, v1);
  #pragma unroll
  for (int off = 32; off; off >>= 1) m = fmaxf(m, __shfl_xor(m, off, 64));
  int wv = t >> 6, ll = t & 63;
  if (ll == 0) redm[wv] = m;
  __syncthreads();
  float bm = redm[0];
  #pragma unroll
  for (int i = 1; i < 8; ++i) bm = fmaxf(bm, redm[i]);
  float e0 = __expf(v0 - bm), e1 = __expf(v1 - bm);
  float s2 = e0 + e1;
  #pragma unroll
  for (int off = 32; off; off >>= 1) s2 += __shfl_xor(s2, off, 64);
  if (ll == 0) reds[wv] = s2;
  __syncthreads();
  float tot = 0.f;
  #pragma unroll
  for (int i = 0; i < 8; ++i) tot += reds[i];
  float inv = 1.f / tot;
  mcol[b*1024 + t]       = e0 * inv;
  mcol[b*1024 + 512 + t] = e1 * inv;
}

// =================== LAUNCH C: k_w1 (38 blocks) ===================
// w1part[i][c] = sum_{d in [8i, 8i+8) ∩ [0,300)} n1[d] * WG1[d][c]
__global__ __launch_bounds__(256) void k_w1(const float* n1g, const float* WG1,
                                            float* w1part) {
  int t = threadIdx.x, i = blockIdx.x, d0 = i*8;
  float acc = 0.f;
  #pragma unroll
  for (int k = 0; k < 8; ++k) {
    int d = d0 + k;
    if (d < 300) acc += n1g[d] * WG1[d*256 + t];
  }
  w1part[i*256 + t] = acc;
}

// =================== LAUNCH D: k_gu (8 blocks) ===================
// Each block: w1 = bg1 + sum of 38 partials; g1 full; h2/g2/rg for its
// 32-col slice; upart[block][o] = partial u over its k-slice.
__global__ __launch_bounds__(256) void k_gu(const float* w1part,
    const float* bg1, const float* AE1g, const float* rsAg, const float* adjng,
    const float* gc2_w, const float* final_w, float* upart) {
  __shared__ float adjns[400], rsAs[32], w1s[256], h2s[640], rgs[32];
  __shared__ float g1s[5120];
  int t = threadIdx.x, c0 = blockIdx.x * 32;
  for (int i = t; i < 400; i += 256) adjns[i] = adjng[i];
  if (t < 20) rsAs[t] = rsAg[t];
  {  // w1 = bg1 + sum of partials
    float acc = bg1[t];
    #pragma unroll
    for (int i = 0; i < 38; ++i) acc += w1part[i*256 + t];
    w1s[t] = acc;
  }
  __syncthreads();
  for (int i = t; i < 5120; i += 256) {
    int n = i >> 8;
    g1s[i] = fmaxf(AE1g[i] + rsAs[n] * w1s[i & 255], 0.f);
  }
  __syncthreads();
  int cl = t & 31, ng = t >> 5;
  float a0 = 0.f, a1 = 0.f, a2 = 0.f;
  for (int d = 0; d < 256; ++d) {
    float wv = gc2_w[d*256 + c0 + cl];
    a0 += g1s[ng*256 + d] * wv;
    a1 += g1s[(ng + 8)*256 + d] * wv;
    if (ng < 4) a2 += g1s[(ng + 16)*256 + d] * wv;
  }
  h2s[ng*32 + cl] = a0;
  h2s[(ng + 8)*32 + cl] = a1;
  if (ng < 4) h2s[(ng + 16)*32 + cl] = a2;
  __syncthreads();
  if (t < 32) {
    float rga = 0.f;
    for (int n = 0; n < 20; ++n) {
      float acc = 0.f;
      #pragma unroll
      for (int m = 0; m < 20; ++m) acc += adjns[n*20 + m] * h2s[m*32 + t];
      rga += fmaxf(acc, 0.f);
    }
    rgs[t] = rga;
  }
  __syncthreads();
  {  // upart over this block's k-slice
    float acc = 0.f;
    const float* fw = final_w + t*512 + 256 + c0;
    #pragma unroll
    for (int kk = 0; kk < 32; ++kk) acc += fw[kk] * rgs[kk];
    upart[blockIdx.x*256 + t] = acc;
  }
}

// =================== LAUNCH E: k_main ===================
// S[p,q] = sum_m e'[p,m] f[m,q] (MFMA) + 0.5*a[p]*c[q]; E=exp(S-Mb); rowsum;
// S2u += E @ x_r; T = x_r - S2u/rs; out = relu(M@T^T + mcol*u + x).
// p-tile 32, grid (32,16) = 512 blocks (2/CU), XCD remap (2 batches/XCD).
// 2 st per barrier (16 barriers); bv/a0 prefetched one super-iter ahead.
__global__ __launch_bounds__(256) void k_main(const float* x, const bf16_t* fB,
    const bf16_t* fBT, const bf16_t* xT, const bf16_t* M16, const float* fmaxb,
    const float* mcol, const float* upart, const float* dgd, const float* csum,
    const float* cmaxb, float* out) {
  int flat = blockIdx.y * 32 + blockIdx.x;
  int b  = (flat & 7) * 2 + ((flat >> 3) >> 5);   // bijective XCD remap
  int p0 = ((flat >> 3) & 31) * 32;
  int t = threadIdx.x, w = t >> 6, l = t & 63, lr = l & 15, quad = l >> 4;
  int qh = w >> 1, ph = w & 1;
  __shared__ __align__(16) char smem[16896];       // union: {PT dbuf(2x2 tiles) | e_s} / T_ls
  bf16_t* PT0  = (bf16_t*)smem;                    // 2 buf x 2 tiles x [32][40]
  bf16_t* e_s  = (bf16_t*)(smem + 10240);          // [32][40] (m>=16 zero)
  bf16_t* T_ls = (bf16_t*)smem;                    // [32][264] phase 2
  __shared__ float Mb_s[32], fmax_s[16], u_s[256], rsinv_s[32], dgd_s[16];
  __shared__ float c_s[1024], ha_s[32], rs_s[2][32];
  const float*  xb   = x   + b*262144;
  const bf16_t* fBb  = fB  + b*16384;
  const bf16_t* fBTb = fBT + b*16384;
  const bf16_t* xTb  = xT  + b*262144;
  for (int i = t; i < 1280; i += 256) e_s[i] = (bf16_t)0.f;
  {
    float us = 0.f;
    #pragma unroll
    for (int j = 0; j < 8; ++j) us += upart[j*256 + t];
    u_s[t] = us;
  }
  for (int i = t; i < 1024; i += 256) c_s[i] = csum[b*1024 + i];
  if (t < 16) { fmax_s[t] = fmaxb[b*16 + t]; dgd_s[t] = dgd[b*16 + t]; }
  __syncthreads();
  for (int i = t; i < 512; i += 256) {       // e'[p,m] = x_phi * (sig(g[m])-0.5)
    int p = i >> 4, m = i & 15;
    e_s[p*40 + m] = (bf16_t)((float)fBb[p0*16 + i] * dgd_s[m]);
  }
  __syncthreads();
  if (t < 32) {
    float a = 0.f;
    #pragma unroll
    for (int m = 0; m < 16; ++m) a += (float)fBb[(p0 + t)*16 + m];
    float ha = 0.5f * a;
    ha_s[t] = ha;
    float mb = ha * cmaxb[b];
    #pragma unroll
    for (int m = 0; m < 16; ++m) mb += fmaxf((float)e_s[t*40 + m], 0.f) * fmax_s[m];
    Mb_s[t] = mb;  // exact upper bound on row max of S
  }
  __syncthreads();
  bf16x8 be = *(const bf16x8*)(e_s + (ph*16 + lr)*40 + quad*8);
  float mb_lane = Mb_s[ph*16 + lr];
  float ha_lane = ha_s[ph*16 + lr];
  float rs = 0.f;
  f32x4 acc[2][4];  // S2u[p = pf*16+quad*4+r][c = w*64+cf*16+lr]
  #pragma unroll
  for (int i = 0; i < 2; ++i)
    #pragma unroll
    for (int j = 0; j < 4; ++j) acc[i][j] = (f32x4){0.f, 0.f, 0.f, 0.f};
  bf16x8 zer;
  #pragma unroll
  for (int j = 0; j < 8; ++j) zer[j] = (bf16_t)0.f;
  bf16x8 a0[2], a0n[2];
  a0[0] = a0[1] = a0n[0] = a0n[1] = zer;
  if (quad < 2) {
    a0[0] = *(const bf16x8*)(fBTb + (qh*16 + lr)*16 + quad*8);
    a0[1] = *(const bf16x8*)(fBTb + (32 + qh*16 + lr)*16 + quad*8);
  }
  const bf16_t* xrow = xTb + (w*64 + lr)*1024 + quad*8;
  bf16x8 bv[2][4], bvn[2][4];
  #pragma unroll
  for (int k = 0; k < 2; ++k)
    #pragma unroll
    for (int cf = 0; cf < 4; ++cf)
      bv[k][cf] = *(const bf16x8*)(xrow + cf*16384 + k*32);
  int cur = 0;
  for (int u2 = 0; u2 < 16; ++u2) {
    f32x4 z = {0.f, 0.f, 0.f, 0.f};
    f32x4 s0 = MFMA(a0[0], be, z);   // D[q=(2u2)*32+qh*16+quad*4+r][p=ph*16+lr]
    f32x4 s1 = MFMA(a0[1], be, z);   // st 2u2+1
    if (u2 < 15) {                   // prefetch next super-iter (lands during barrier)
      if (quad < 2) {
        a0n[0] = *(const bf16x8*)(fBTb + ((u2*2 + 2)*32 + qh*16 + lr)*16 + quad*8);
        a0n[1] = *(const bf16x8*)(fBTb + ((u2*2 + 3)*32 + qh*16 + lr)*16 + quad*8);
      }
      #pragma unroll
      for (int k = 0; k < 2; ++k)
        #pragma unroll
        for (int cf = 0; cf < 4; ++cf)
          bvn[k][cf] = *(const bf16x8*)(xrow + cf*16384 + (u2*2 + 2 + k)*32);
    }
    bf16_t* PTc = PT0 + cur*2560;
    bf16x4 pv0, pv1;
    #pragma unroll
    for (int r = 0; r < 4; ++r) {
      float S0 = s0[r] + ha_lane * c_s[(u2*2)*32 + qh*16 + quad*4 + r];
      float E0 = __expf(S0 - mb_lane);
      rs += E0; pv0[r] = (bf16_t)E0;
      float S1 = s1[r] + ha_lane * c_s[(u2*2 + 1)*32 + qh*16 + quad*4 + r];
      float E1v = __expf(S1 - mb_lane);
      rs += E1v; pv1[r] = (bf16_t)E1v;
    }
    *(bf16x4*)(PTc + (ph*16 + lr)*40 + qh*16 + quad*4)        = pv0;
    *(bf16x4*)(PTc + 1280 + (ph*16 + lr)*40 + qh*16 + quad*4) = pv1;
    __syncthreads();
    #pragma unroll
    for (int k = 0; k < 2; ++k) {
      bf16x8 ap0 = *(const bf16x8*)(PTc + k*1280 + lr*40 + quad*8);
      bf16x8 ap1 = *(const bf16x8*)(PTc + k*1280 + (16 + lr)*40 + quad*8);
      #pragma unroll
      for (int cf = 0; cf < 4; ++cf) {
        acc[0][cf] = MFMA(ap0, bv[k][cf], acc[0][cf]);
        acc[1][cf] = MFMA(ap1, bv[k][cf], acc[1][cf]);
      }
    }
    if (u2 < 15) {
      #pragma unroll
      for (int k = 0; k < 2; ++k) {
        a0[k] = a0n[k];
        #pragma unroll
        for (int cf = 0; cf < 4; ++cf) bv[k][cf] = bvn[k][cf];
      }
    }
    cur ^= 1;
  }
  rs += __shfl_xor(rs, 16, 64);
  rs += __shfl_xor(rs, 32, 64);          // qh-half rowsum for p = ph*16+lr
  if (l < 16) rs_s[qh][ph*16 + lr] = rs;
  __syncthreads();   // rs staged; all PT/e_s reads drained -> T_ls may overwrite
  if (t < 32) rsinv_s[t] = 1.f / fmaxf(rs_s[0][t] + rs_s[1][t], 1e-30f);
  __syncthreads();
  #pragma unroll
  for (int pf = 0; pf < 2; ++pf)
    #pragma unroll
    for (int cf = 0; cf < 4; ++cf)
      #pragma unroll
      for (int r = 0; r < 4; ++r) {
        int p = pf*16 + quad*4 + r;
        int c = w*64 + cf*16 + lr;
        float tv = xb[(p0 + p)*256 + c] - acc[pf][cf][r] * rsinv_s[p];
        T_ls[p*264 + c] = (bf16_t)tv;    // spiral[p][c]
      }
  __syncthreads();
  f32x4 acc2[4][2];  // D2[o = w*64+of*16+quad*4+r][p = pf*16+lr]
  #pragma unroll
  for (int i = 0; i < 4; ++i)
    #pragma unroll
    for (int j = 0; j < 2; ++j) acc2[i][j] = (f32x4){0.f, 0.f, 0.f, 0.f};
  for (int c0 = 0; c0 < 256; c0 += 32) {
    bf16x8 am[4], bt[2];
    #pragma unroll
    for (int of = 0; of < 4; ++of)
      am[of] = *(const bf16x8*)(M16 + (w*64 + of*16 + lr)*256 + c0 + quad*8);
    #pragma unroll
    for (int pf = 0; pf < 2; ++pf)
      bt[pf] = *(const bf16x8*)(T_ls + (pf*16 + lr)*264 + c0 + quad*8);
    #pragma unroll
    for (int of = 0; of < 4; ++of)
      #pragma unroll
      for (int pf = 0; pf < 2; ++pf) acc2[of][pf] = MFMA(am[of], bt[pf], acc2[of][pf]);
  }
  float* outb = out + b*262144;
  #pragma unroll
  for (int of = 0; of < 4; ++of)
    #pragma unroll
    for (int pf = 0; pf < 2; ++pf)
      #pragma unroll
      for (int r = 0; r < 4; ++r) {
        int o = w*64 + of*16 + quad*4 + r;
        int pg = p0 + pf*16 + lr;
        float v = acc2[of][pf][r] + mcol[b*1024 + pg] * u_s[o] + xb[o*1024 + pg];
        outb[o*1024 + pg] = fmaxf(v, 0.f);
      }
}

// ---------------- launch ----------------

extern "C" void kernel_launch(void* const* d_in, const int* in_sizes, int n_in,
                              void* d_out, int out_size, void* d_ws, size_t ws_size,
                              hipStream_t stream) {
  (void)in_sizes; (void)n_in; (void)out_size; (void)ws_size;
  const float* x       = (const float*)d_in[0];
  const float* emb     = (const float*)d_in[1];
  const float* adj     = (const float*)d_in[2];
  const float* wq      = (const float*)d_in[3];
  const float* bq      = (const float*)d_in[4];
  const float* wk      = (const float*)d_in[5];
  const float* bk      = (const float*)d_in[6];
  const float* wv      = (const float*)d_in[7];
  const float* bv      = (const float*)d_in[8];
  const float* wo      = (const float*)d_in[9];
  const float* bo      = (const float*)d_in[10];
  const float* phi_w   = (const float*)d_in[11];
  const float* phi_b   = (const float*)d_in[12];
  const float* glob_w  = (const float*)d_in[13];
  const float* gc1_w   = (const float*)d_in[14];
  const float* gc2_w   = (const float*)d_in[15];
  const float* gw_w    = (const float*)d_in[16];
  const float* s2l_w   = (const float*)d_in[17];
  const float* final_w = (const float*)d_in[19];
  float* out = (float*)d_out;

  float* W = (float*)d_ws;
  float* qkv    = W + 0;        // 18000 -> 18048
  float* xsump  = W + 18048;    // 32768 -> 50816
  float* s_raw  = W + 50816;    // 16384 -> 67200
  float* mcol   = W + 67200;    // 16384 -> 83584
  float* fmaxb  = W + 83584;    // 256   -> 83840
  float* dgd    = W + 83840;    // 256   -> 84096
  float* csum   = W + 84096;    // 16384 -> 100480
  float* cmaxb  = W + 100480;   // 64    -> 100544
  float* fmaxp  = W + 100544;   // 2048  -> 102592
  float* cmaxp  = W + 102592;   // 128   -> 102720
  float* E1     = W + 102720;   // 5120  -> 107840
  float* WG1    = W + 107840;   // 76800 -> 184640
  float* bg1    = W + 184640;   // 256   -> 184896
  float* n1     = W + 184896;   // 320   -> 185216
  float* adjn   = W + 185216;   // 448   -> 185664
  float* rsA    = W + 185664;   // 64    -> 185728
  float* AE1    = W + 185728;   // 5120  -> 190848
  float* upart  = W + 190848;   // 2048  -> 192896
  float* w1part = W + 192896;   // 9728  -> 202624 floats (810496 B)
  bf16_t* M16 = (bf16_t*)((char*)d_ws + 851968);   // 128 KB
  bf16_t* fB  = (bf16_t*)((char*)d_ws + 983040);   // 512 KB (m-major raw)
  bf16_t* fBT = (bf16_t*)((char*)d_ws + 1507328);  // 512 KB (q-major)
  bf16_t* xT  = (bf16_t*)((char*)d_ws + 2031616);  // 8 MB  (x transposed bf16)
  // total ws usage ~9.95 MB

  k_front<<<1789, 256, 0, stream>>>(final_w, gw_w, emb, wq, bq, wk, bk, wv, bv, x,
                                    phi_w, phi_b, s2l_w, gc1_w, wo, bo,
                                    M16, qkv, fB, fBT, s_raw, xsump, csum,
                                    fmaxp, cmaxp, xT, E1, WG1, bg1);
  k_mid1<<<18, 512, 0, stream>>>(adj, qkv, E1, glob_w, xsump, s_raw,
                                 fmaxp, cmaxp,
                                 n1, adjn, rsA, AE1, dgd, mcol, fmaxb, cmaxb);
  k_w1<<<38, 256, 0, stream>>>(n1, WG1, w1part);
  k_gu<<<8, 256, 0, stream>>>(w1part, bg1, AE1, rsA, adjn, gc2_w, final_w, upart);
  k_main<<<dim3(32, 16), 256, 0, stream>>>(x, fB, fBT, xT, M16, fmaxb, mcol, upart,
                                           dgd, csum, cmaxb, out);
}

// Round 7
// 228.918 us; speedup vs baseline: 1.3031x; 1.0153x over previous
//
#include <hip/hip_runtime.h>
#include <hip/hip_bf16.h>

// Inputs/outputs are FLOAT32 (reference dtype). bf16 used only internally for MFMA.
typedef __bf16 bf16_t;
typedef bf16_t bf16x8 __attribute__((ext_vector_type(8)));
typedef bf16_t bf16x4 __attribute__((ext_vector_type(4)));
typedef float  f32x4  __attribute__((ext_vector_type(4)));

#define MFMA(a,b,c) __builtin_amdgcn_mfma_f32_16x16x32_bf16((a),(b),(c),0,0,0)

// =================== LAUNCH A: k_front (1789 blocks) ===================
// roles by blockIdx.x:
//   [0,256)     : M = final_w[:, :256] @ gw_w  (bf16)
//   [256,316)   : qkv = emb @ {wq,wk,wv} + bias
//   [316,444)   : phis (8 roles x 16 b): fB, fBT, s_raw, csum, fmax/cmax, xsump
//   [444,464)   : E1 = emb @ gc1_w  [20][256]
//   [464,765)   : WG1 = wo @ gc1_w [300][256]; row 300 = bg1 = bo @ gc1_w
//   [765,1789)  : xT transpose: raw [1024q][256c] fp32 -> xT [256c][1024q] bf16
__global__ __launch_bounds__(256) void k_front(
    const float* final_w, const float* gw_w, const float* emb,
    const float* wq, const float* bq, const float* wk, const float* bk,
    const float* wv, const float* bvv, const float* x,
    const float* phi_w, const float* phi_b, const float* s2l_w,
    const float* gc1_w, const float* wo, const float* bo,
    bf16_t* M16, float* qkv, bf16_t* fB, bf16_t* fBT, float* s_raw,
    float* xsump, float* csum, float* fmaxp, float* cmaxp, bf16_t* xT,
    float* E1, float* WG1, float* bg1) {
  __shared__ __align__(16) char sp[27648];
  int bid = blockIdx.x, t = threadIdx.x;
  if (bid < 256) {                       // ---- k_M ----
    float* fw = (float*)sp;
    int o = bid, c = t;
    fw[c] = final_w[o*512 + c];
    __syncthreads();
    float acc = 0.f;
    for (int k = 0; k < 256; ++k) acc += fw[k] * gw_w[k*256 + c];
    M16[o*256 + c] = (bf16_t)acc;
    return;
  }
  if (bid < 316) {                       // ---- k_qkv ----
    int id = bid - 256;
    int mat = id / 20, row = id % 20;
    const float* W  = mat == 0 ? wq : (mat == 1 ? wk : wv);
    const float* Bb = mat == 0 ? bq : (mat == 1 ? bk : bvv);
    float* er = (float*)sp;
    for (int i = t; i < 300; i += 256) er[i] = emb[row*300 + i];
    __syncthreads();
    for (int o = t; o < 300; o += 256) {
      float acc = Bb[o];
      for (int d = 0; d < 300; ++d) acc += er[d] * W[d*300 + o];
      qkv[(mat*20 + row)*300 + o] = acc;
    }
    return;
  }
  if (bid < 444) {                       // ---- k_phis ----
    int id = bid - 316;
    int b = id >> 3, role = id & 7;
    const float* xb = x + b*262144;
    float* pw = (float*)sp;              // 4096
    float* wi = pw + 4096;               // 256
    float* pb = wi + 256;                // 16
    float* phs = pb + 16;                // [128][18]
    unsigned* fmu = (unsigned*)(phs + 2304);  // 16
    unsigned* cmu = fmu + 16;            // 1
    for (int i = t; i < 4096; i += 256) pw[i] = phi_w[i];
    wi[t] = s2l_w[t];
    if (t < 16) { pb[t] = phi_b[t]; fmu[t] = 0u; }
    if (t == 0) cmu[0] = 0u;
    __syncthreads();
    int hwl = t & 127, half = t >> 7;
    int hw = role*128 + hwl;
    float ph[16];
    #pragma unroll
    for (int o = 0; o < 16; ++o) ph[o] = 0.f;
    float sacc = 0.f;
    for (int ci = 0; ci < 128; ++ci) {
      int c = half*128 + ci;
      float xv = xb[c*1024 + hw];
      sacc += wi[c] * xv;
      #pragma unroll
      for (int o = 0; o < 16; ++o) ph[o] += pw[o*256 + c] * xv;
    }
    if (half == 0) {
      #pragma unroll
      for (int o = 0; o < 16; ++o) phs[hwl*18 + o] = ph[o];
      phs[hwl*18 + 16] = sacc;
    }
    __syncthreads();
    if (half == 1) {
      #pragma unroll
      for (int o = 0; o < 16; ++o) phs[hwl*18 + o] += ph[o];
      s_raw[b*1024 + hw] = phs[hwl*18 + 16] + sacc;
    }
    __syncthreads();
    float csacc = 0.f;
    #pragma unroll
    for (int i = 0; i < 8; ++i) {
      int j = i*256 + t;
      int o = j >> 7, hl = j & 127;
      float val = fmaxf(phs[hl*18 + o] + pb[o], 0.f);
      bf16_t bv16 = (bf16_t)val;
      atomicMax(&fmu[o], __float_as_uint((float)bv16));
      fB [b*16384 + o*1024 + role*128 + hl] = bv16;            // m-major (raw)
      fBT[b*16384 + (role*128 + hl)*16 + o] = bv16;            // q-major
      csacc += (float)bv16;
    }
    if (half == 0) phs[hwl*18 + 17] = csacc;
    __syncthreads();
    if (half == 1) {
      float cs = phs[hwl*18 + 17] + csacc;
      csum[b*1024 + hw] = cs;
      atomicMax(cmu, __float_as_uint(cs));
    }
    if (t < 16) fmaxp[b*128 + role*16 + t] = __uint_as_float(fmu[t]);
    __syncthreads();
    if (t == 0) cmaxp[b*8 + role] = __uint_as_float(cmu[0]);
    // xsum partial for this (b, role): L2-hot re-read, thread owns channel c = t
    {
      const f32x4* xr = (const f32x4*)(xb + t*1024 + role*128);
      float s4 = 0.f;
      #pragma unroll
      for (int j = 0; j < 32; ++j) { f32x4 v = xr[j]; s4 += v[0] + v[1] + v[2] + v[3]; }
      xsump[(b*8 + role)*256 + t] = s4;
    }
    return;
  }
  if (bid < 464) {                       // ---- E1 = emb @ gc1_w ----
    int n = bid - 444;
    float* er = (float*)sp;
    for (int i = t; i < 300; i += 256) er[i] = emb[n*300 + i];
    __syncthreads();
    float acc = 0.f;
    for (int d = 0; d < 300; ++d) acc += er[d] * gc1_w[d*256 + t];
    E1[n*256 + t] = acc;
    return;
  }
  if (bid < 765) {                       // ---- WG1 rows / bg1 ----
    int d0 = bid - 464;                  // 0..300
    float* er = (float*)sp;
    if (d0 < 300) { for (int i = t; i < 300; i += 256) er[i] = wo[d0*300 + i]; }
    else          { for (int i = t; i < 300; i += 256) er[i] = bo[i]; }
    __syncthreads();
    float acc = 0.f;
    for (int e = 0; e < 300; ++e) acc += er[e] * gc1_w[e*256 + t];
    if (d0 < 300) WG1[d0*256 + t] = acc; else bg1[t] = acc;
    return;
  }
  {                                      // ---- k_xt: raw-reshape transpose ----
    int id = bid - 765;                  // 0..1023
    int bb = id >> 6, tile = id & 63;
    int q0 = (tile >> 2) * 64, c0 = (tile & 3) * 64;
    bf16_t* tl = (bf16_t*)sp;            // [64][74]
    const float* xbb = x + bb*262144;
    #pragma unroll
    for (int k = 0; k < 16; ++k) {
      int idx = k*256 + t, qi = idx >> 6, ci = idx & 63;
      tl[ci*74 + qi] = (bf16_t)xbb[(q0 + qi)*256 + c0 + ci];
    }
    __syncthreads();
    #pragma unroll
    for (int k = 0; k < 16; ++k) {
      int idx = k*256 + t, ci = idx >> 6, qi = idx & 63;
      xT[bb*262144 + (c0 + ci)*1024 + q0 + qi] = tl[ci*74 + qi];
    }
    return;
  }
}

// =================== LAUNCH B: k_mid1 (18 blocks x 512) ===================
__global__ __launch_bounds__(512) void k_mid1(
    const float* adj, const float* qkv, const float* E1,
    const float* glob_w, const float* xsump, const float* s_raw,
    const float* fmaxp, const float* cmaxp,
    float* n1g, float* adjng, float* rsAg, float* AE1g,
    float* dgd, float* mcol, float* fmaxb, float* cmaxb) {
  __shared__ __align__(16) float sp[12480];
  int t = threadIdx.x;
  if (blockIdx.x == 0) {                 // ---- attention -> n1 ----
    float* A  = sp;            // 6000 q
    float* Bs = A + 6000;      // 6000 k
    float* att  = Bs + 6000;   // 400
    float* wsum = att + 400;   // 20
    for (int i = t; i < 6000; i += 512) { A[i] = qkv[i]; Bs[i] = qkv[6000 + i]; }
    __syncthreads();
    if (t < 400) {
      int i = t / 20, j = t % 20;
      float acc = 0.f;
      for (int d = 0; d < 300; ++d) acc += A[i*300 + d] * Bs[j*300 + d];
      att[t] = acc * 0.05773502691896258f;  // 1/sqrt(300)
    }
    __syncthreads();
    if (t < 20) {
      float m = -1e30f;
      for (int j = 0; j < 20; ++j) m = fmaxf(m, att[t*20 + j]);
      float s = 0.f;
      for (int j = 0; j < 20; ++j) { float e = __expf(att[t*20 + j] - m); att[t*20 + j] = e; s += e; }
      float inv = 1.f / s;
      for (int j = 0; j < 20; ++j) att[t*20 + j] *= inv;
    }
    __syncthreads();
    if (t < 20) {
      float s = 0.f;
      for (int i = 0; i < 20; ++i) s += att[i*20 + t];
      wsum[t] = s * 0.05f;
    }
    __syncthreads();
    if (t < 300) {
      const float* v = qkv + 12000;
      float acc = 0.f;
      for (int j = 0; j < 20; ++j) acc += wsum[j] * v[j*300 + t];
      n1g[t] = acc;
    }
    return;
  }
  if (blockIdx.x == 1) {                 // ---- adjn / rsA / AE1 ----
    float* drt = sp;           // 20
    float* an  = sp + 32;      // 400
    if (t < 20) {
      float s = 1.f;
      for (int j = 0; j < 20; ++j) s += adj[t*20 + j];
      drt[t] = rsqrtf(s);
    }
    __syncthreads();
    if (t < 400) {
      int i = t / 20, j = t % 20;
      float a = adj[t] + (i == j ? 1.f : 0.f);
      float v = drt[i] * a * drt[j];
      an[t] = v;
      adjng[t] = v;
    }
    __syncthreads();
    if (t < 20) {
      float s = 0.f;
      for (int m = 0; m < 20; ++m) s += an[t*20 + m];
      rsAg[t] = s;
    }
    if (t < 256) {
      float e[20];
      #pragma unroll
      for (int m = 0; m < 20; ++m) e[m] = E1[m*256 + t];
      for (int n = 0; n < 20; ++n) {
        float acc = 0.f;
        #pragma unroll
        for (int m = 0; m < 20; ++m) acc += an[n*20 + m] * e[m];
        AE1g[n*256 + t] = acc;
      }
    }
    return;
  }
  // ---- dgm + fmax/cmax reduce, b = blockIdx.x-2 ----
  int b = blockIdx.x - 2;
  float* xm = sp;            // 256
  float* redm = xm + 256;    // 8
  float* reds = redm + 8;    // 8
  if (t < 256) {
    float s = 0.f;
    #pragma unroll
    for (int r = 0; r < 8; ++r) s += xsump[(b*8 + r)*256 + t];
    xm[t] = s * (1.f / 1024.f);
  }
  if (t >= 256 && t < 272) {
    int m = t - 256; float fm = 0.f;
    for (int r = 0; r < 8; ++r) fm = fmaxf(fm, fmaxp[b*128 + r*16 + m]);
    fmaxb[b*16 + m] = fm;
  }
  if (t == 272) {
    float cm = 0.f;
    for (int r = 0; r < 8; ++r) cm = fmaxf(cm, cmaxp[b*8 + r]);
    cmaxb[b] = cm;
  }
  __syncthreads();
  if (t < 16) {
    float g = 0.f;
    for (int c = 0; c < 256; ++c) g += glob_w[t*256 + c] * xm[c];
    dgd[b*16 + t] = 0.5f * tanhf(0.5f * g);   // sigmoid(g) - 0.5
  }
  float v0 = s_raw[b*1024 + t], v1 = s_raw[b*1024 + 512 + t];
  float m = fmaxf(v0, v1);
  #pragma unroll
  for (int off = 32; off; off >>= 1) m = fmaxf(m, __shfl_xor(m, off, 64));
  int wv = t >> 6, ll = t & 63;
  if (ll == 0) redm[wv] = m;
  __syncthreads();
  float bm = redm[0];
  #pragma unroll
  for (int i = 1; i < 8; ++i) bm = fmaxf(bm, redm[i]);
  float e0 = __expf(v0 - bm), e1 = __expf(v1 - bm);
  float s2 = e0 + e1;
  #pragma unroll
  for (int off = 32; off; off >>= 1) s2 += __shfl_xor(s2, off, 64);
  if (ll == 0) reds[wv] = s2;
  __syncthreads();
  float tot = 0.f;
  #pragma unroll
  for (int i = 0; i < 8; ++i) tot += reds[i];
  float inv = 1.f / tot;
  mcol[b*1024 + t]       = e0 * inv;
  mcol[b*1024 + 512 + t] = e1 * inv;
}

// =================== LAUNCH C: k_w1 (38 blocks) ===================
// w1part[i][c] = sum_{d in [8i, 8i+8) ∩ [0,300)} n1[d] * WG1[d][c]
__global__ __launch_bounds__(256) void k_w1(const float* n1g, const float* WG1,
                                            float* w1part) {
  int t = threadIdx.x, i = blockIdx.x, d0 = i*8;
  float acc = 0.f;
  #pragma unroll
  for (int k = 0; k < 8; ++k) {
    int d = d0 + k;
    if (d < 300) acc += n1g[d] * WG1[d*256 + t];
  }
  w1part[i*256 + t] = acc;
}

// =================== LAUNCH D: k_gu (32 blocks, 8-col slices) ===================
// Each block: w1 full (38 partial sums); g1 full in LDS; gc2_w 8-col slice
// staged in LDS; h2/g2/rg for its slice; upart[block][o] over its k-slice.
__global__ __launch_bounds__(256) void k_gu(const float* w1part,
    const float* bg1, const float* AE1g, const float* rsAg, const float* adjng,
    const float* gc2_w, const float* final_w, float* upart) {
  __shared__ float adjns[400], rsAs[32], w1s[256], h2s[176], rgs[8];
  __shared__ float g1s[20*260];   // rows padded to 260 (8 distinct banks for 8 n's)
  __shared__ float gs2[2048];     // [256 d][8 cl]
  int t = threadIdx.x, c0 = blockIdx.x * 8;
  for (int i = t; i < 400; i += 256) adjns[i] = adjng[i];
  if (t < 20) rsAs[t] = rsAg[t];
  #pragma unroll
  for (int k2 = 0; k2 < 8; ++k2) {       // stage gc2 slice (independent loads)
    int idx = k2*256 + t, d = idx >> 3, cl = idx & 7;
    gs2[idx] = gc2_w[d*256 + c0 + cl];
  }
  {                                      // w1 = bg1 + sum of partials
    float acc = bg1[t];
    #pragma unroll
    for (int i = 0; i < 38; ++i) acc += w1part[i*256 + t];
    w1s[t] = acc;
  }
  float ae[20];
  #pragma unroll
  for (int k2 = 0; k2 < 20; ++k2) ae[k2] = AE1g[k2*256 + t];
  __syncthreads();
  #pragma unroll
  for (int k2 = 0; k2 < 20; ++k2)
    g1s[k2*260 + t] = fmaxf(ae[k2] + rsAs[k2] * w1s[t], 0.f);
  __syncthreads();
  int cl = t & 7, n = t >> 3;            // n 0..32, use n<20
  if (n < 20) {
    float acc = 0.f;
    for (int d = 0; d < 256; ++d) acc += g1s[n*260 + d] * gs2[d*8 + cl];
    h2s[n*8 + cl] = acc;
  }
  __syncthreads();
  if (t < 8) {
    float rga = 0.f;
    for (int nn = 0; nn < 20; ++nn) {
      float a2 = 0.f;
      #pragma unroll
      for (int m = 0; m < 20; ++m) a2 += adjns[nn*20 + m] * h2s[m*8 + t];
      rga += fmaxf(a2, 0.f);
    }
    rgs[t] = rga;
  }
  __syncthreads();
  {                                      // upart over this block's 8-k slice
    float acc = 0.f;
    const float* fw = final_w + t*512 + 256 + c0;
    #pragma unroll
    for (int kk = 0; kk < 8; ++kk) acc += fw[kk] * rgs[kk];
    upart[blockIdx.x*256 + t] = acc;
  }
}

// =================== LAUNCH E: k_main (barrier-free st loop) ===================
// Waves = (ph = p-half, ch = c-half). Each wave: S for ALL 32 q of its p-half
// (2 MFMAs), E lane-local, in-wave shuffle to A-frag, PV over its c-half
// (8 MFMAs). No LDS/barriers inside the 32-iteration loop.
__global__ __launch_bounds__(256) void k_main(const float* x, const bf16_t* fB,
    const bf16_t* fBT, const bf16_t* xT, const bf16_t* M16, const float* fmaxb,
    const float* mcol, const float* upart, const float* dgd, const float* csum,
    const float* cmaxb, float* out) {
  int flat = blockIdx.y * 32 + blockIdx.x;
  int b  = (flat & 7) * 2 + ((flat >> 3) >> 5);   // bijective XCD remap
  int p0 = ((flat >> 3) & 31) * 32;
  int t = threadIdx.x, w = t >> 6, l = t & 63, lr = l & 15, quad = l >> 4;
  int ph = w & 1, ch = w >> 1;
  __shared__ __align__(16) char smem[16896];       // union: e_s / T_ls
  bf16_t* e_s  = (bf16_t*)smem;                    // [32][40] (m>=16 zero)
  bf16_t* T_ls = (bf16_t*)smem;                    // [32][264] phase 2
  __shared__ float Mb_s[32], fmax_s[16], u_s[256], dgd_s[16];
  __shared__ float c_s[1024], ha_s[32];
  const float*  xb   = x   + b*262144;
  const bf16_t* fBb  = fB  + b*16384;
  const bf16_t* fBTb = fBT + b*16384;
  const bf16_t* xTb  = xT  + b*262144;
  for (int i = t; i < 1280; i += 256) e_s[i] = (bf16_t)0.f;
  {
    float us = 0.f;
    #pragma unroll
    for (int j = 0; j < 32; ++j) us += upart[j*256 + t];
    u_s[t] = us;
  }
  for (int i = t; i < 1024; i += 256) c_s[i] = csum[b*1024 + i];
  if (t < 16) { fmax_s[t] = fmaxb[b*16 + t]; dgd_s[t] = dgd[b*16 + t]; }
  __syncthreads();
  for (int i = t; i < 512; i += 256) {       // e'[p,m] = x_phi * (sig(g[m])-0.5)
    int p = i >> 4, m = i & 15;
    e_s[p*40 + m] = (bf16_t)((float)fBb[p0*16 + i] * dgd_s[m]);
  }
  __syncthreads();
  if (t < 32) {
    float a = 0.f;
    #pragma unroll
    for (int m = 0; m < 16; ++m) a += (float)fBb[(p0 + t)*16 + m];
    float ha = 0.5f * a;
    ha_s[t] = ha;
    float mb = ha * cmaxb[b];
    #pragma unroll
    for (int m = 0; m < 16; ++m) mb += fmaxf((float)e_s[t*40 + m], 0.f) * fmax_s[m];
    Mb_s[t] = mb;  // exact upper bound on row max of S
  }
  __syncthreads();
  bf16x8 be = *(const bf16x8*)(e_s + (ph*16 + lr)*40 + quad*8);  // p = ph*16+lr
  float mb_lane = Mb_s[ph*16 + lr];
  float ha_lane = ha_s[ph*16 + lr];
  float rs = 0.f;
  f32x4 acc[8];  // S2u[p = ph*16+quad*4+r][c = ch*128+cf*16+lr]
  #pragma unroll
  for (int j = 0; j < 8; ++j) acc[j] = (f32x4){0.f, 0.f, 0.f, 0.f};
  bf16x8 zer;
  #pragma unroll
  for (int j = 0; j < 8; ++j) zer[j] = (bf16_t)0.f;
  const bf16_t* xrow = xTb + (ch*128 + lr)*1024 + quad*8;
  int srcLo = ((quad & 1) << 5) + lr;   // source lanes for A-frag shuffle
  int srcHi = srcLo + 16;
  bool hi = quad >= 2;
  for (int st = 0; st < 32; ++st) {
    bf16x8 a0 = zer, a1 = zer;
    if (quad < 2) {
      a0 = *(const bf16x8*)(fBTb + (st*32 + lr)*16 + quad*8);
      a1 = *(const bf16x8*)(fBTb + (st*32 + 16 + lr)*16 + quad*8);
    }
    bf16x8 bv[8];
    #pragma unroll
    for (int cf = 0; cf < 8; ++cf)
      bv[cf] = *(const bf16x8*)(xrow + cf*16384 + st*32);
    f32x4 z = {0.f, 0.f, 0.f, 0.f};
    f32x4 s0 = MFMA(a0, be, z);   // D[q=st*32+quad*4+r][p=ph*16+lr]
    f32x4 s1 = MFMA(a1, be, z);   // q = st*32+16+quad*4+r
    float E0[4], E1v[4];
    #pragma unroll
    for (int r = 0; r < 4; ++r) {
      float S0 = s0[r] + ha_lane * c_s[st*32 + quad*4 + r];
      float S1 = s1[r] + ha_lane * c_s[st*32 + 16 + quad*4 + r];
      E0[r] = __expf(S0 - mb_lane);
      E1v[r] = __expf(S1 - mb_lane);
      rs += E0[r] + E1v[r];
    }
    unsigned P0, P1, P2, P3;
    {
      union { bf16_t h[2]; unsigned u; } pk;
      pk.h[0] = (bf16_t)E0[0];  pk.h[1] = (bf16_t)E0[1];  P0 = pk.u;
      pk.h[0] = (bf16_t)E0[2];  pk.h[1] = (bf16_t)E0[3];  P1 = pk.u;
      pk.h[0] = (bf16_t)E1v[0]; pk.h[1] = (bf16_t)E1v[1]; P2 = pk.u;
      pk.h[0] = (bf16_t)E1v[2]; pk.h[1] = (bf16_t)E1v[3]; P3 = pk.u;
    }
    // A-frag redistribution: lane (quad,lr) needs E[p=lr][q=quad*8+j]
    unsigned xA = (unsigned)__shfl((int)P0, srcLo, 64);
    unsigned xB = (unsigned)__shfl((int)P2, srcLo, 64);
    unsigned yA = (unsigned)__shfl((int)P1, srcLo, 64);
    unsigned yB = (unsigned)__shfl((int)P3, srcLo, 64);
    unsigned zA = (unsigned)__shfl((int)P0, srcHi, 64);
    unsigned zB = (unsigned)__shfl((int)P2, srcHi, 64);
    unsigned wA = (unsigned)__shfl((int)P1, srcHi, 64);
    unsigned wB = (unsigned)__shfl((int)P3, srcHi, 64);
    union { unsigned u[4]; bf16x8 v; } af;
    af.u[0] = hi ? xB : xA;
    af.u[1] = hi ? yB : yA;
    af.u[2] = hi ? zB : zA;
    af.u[3] = hi ? wB : wA;
    bf16x8 ap = af.v;
    #pragma unroll
    for (int cf = 0; cf < 8; ++cf) acc[cf] = MFMA(ap, bv[cf], acc[cf]);
  }
  rs += __shfl_xor(rs, 16, 64);
  rs += __shfl_xor(rs, 32, 64);          // full rowsum for p = ph*16+lr (all q in-wave)
  float rsinv = 1.f / fmaxf(rs, 1e-30f);
  float rsv[4];
  #pragma unroll
  for (int r = 0; r < 4; ++r) rsv[r] = __shfl(rsinv, quad*4 + r, 64);
  __syncthreads();   // all e_s/be reads done -> T_ls may overwrite
  #pragma unroll
  for (int cf = 0; cf < 8; ++cf)
    #pragma unroll
    for (int r = 0; r < 4; ++r) {
      int p = ph*16 + quad*4 + r;
      int c = ch*128 + cf*16 + lr;
      float tv = xb[(p0 + p)*256 + c] - acc[cf][r] * rsv[r];
      T_ls[p*264 + c] = (bf16_t)tv;    // spiral[p][c]
    }
  __syncthreads();
  f32x4 acc2[4][2];  // D2[o = w*64+of*16+quad*4+r][p = pf*16+lr]
  #pragma unroll
  for (int i = 0; i < 4; ++i)
    #pragma unroll
    for (int j = 0; j < 2; ++j) acc2[i][j] = (f32x4){0.f, 0.f, 0.f, 0.f};
  for (int c0 = 0; c0 < 256; c0 += 32) {
    bf16x8 am[4], bt[2];
    #pragma unroll
    for (int of = 0; of < 4; ++of)
      am[of] = *(const bf16x8*)(M16 + (w*64 + of*16 + lr)*256 + c0 + quad*8);
    #pragma unroll
    for (int pf = 0; pf < 2; ++pf)
      bt[pf] = *(const bf16x8*)(T_ls + (pf*16 + lr)*264 + c0 + quad*8);
    #pragma unroll
    for (int of = 0; of < 4; ++of)
      #pragma unroll
      for (int pf = 0; pf < 2; ++pf) acc2[of][pf] = MFMA(am[of], bt[pf], acc2[of][pf]);
  }
  float* outb = out + b*262144;
  #pragma unroll
  for (int of = 0; of < 4; ++of)
    #pragma unroll
    for (int pf = 0; pf < 2; ++pf)
      #pragma unroll
      for (int r = 0; r < 4; ++r) {
        int o = w*64 + of*16 + quad*4 + r;
        int pg = p0 + pf*16 + lr;
        float v = acc2[of][pf][r] + mcol[b*1024 + pg] * u_s[o] + xb[o*1024 + pg];
        outb[o*1024 + pg] = fmaxf(v, 0.f);
      }
}

// ---------------- launch ----------------

extern "C" void kernel_launch(void* const* d_in, const int* in_sizes, int n_in,
                              void* d_out, int out_size, void* d_ws, size_t ws_size,
                              hipStream_t stream) {
  (void)in_sizes; (void)n_in; (void)out_size; (void)ws_size;
  const float* x       = (const float*)d_in[0];
  const float* emb     = (const float*)d_in[1];
  const float* adj     = (const float*)d_in[2];
  const float* wq      = (const float*)d_in[3];
  const float* bq      = (const float*)d_in[4];
  const float* wk      = (const float*)d_in[5];
  const float* bk      = (const float*)d_in[6];
  const float* wv      = (const float*)d_in[7];
  const float* bv      = (const float*)d_in[8];
  const float* wo      = (const float*)d_in[9];
  const float* bo      = (const float*)d_in[10];
  const float* phi_w   = (const float*)d_in[11];
  const float* phi_b   = (const float*)d_in[12];
  const float* glob_w  = (const float*)d_in[13];
  const float* gc1_w   = (const float*)d_in[14];
  const float* gc2_w   = (const float*)d_in[15];
  const float* gw_w    = (const float*)d_in[16];
  const float* s2l_w   = (const float*)d_in[17];
  const float* final_w = (const float*)d_in[19];
  float* out = (float*)d_out;

  float* W = (float*)d_ws;
  float* qkv    = W + 0;        // 18000 -> 18048
  float* xsump  = W + 18048;    // 32768 -> 50816
  float* s_raw  = W + 50816;    // 16384 -> 67200
  float* mcol   = W + 67200;    // 16384 -> 83584
  float* fmaxb  = W + 83584;    // 256   -> 83840
  float* dgd    = W + 83840;    // 256   -> 84096
  float* csum   = W + 84096;    // 16384 -> 100480
  float* cmaxb  = W + 100480;   // 64    -> 100544
  float* fmaxp  = W + 100544;   // 2048  -> 102592
  float* cmaxp  = W + 102592;   // 128   -> 102720
  float* E1     = W + 102720;   // 5120  -> 107840
  float* WG1    = W + 107840;   // 76800 -> 184640
  float* bg1    = W + 184640;   // 256   -> 184896
  float* n1     = W + 184896;   // 320   -> 185216
  float* adjn   = W + 185216;   // 448   -> 185664
  float* rsA    = W + 185664;   // 64    -> 185728
  float* AE1    = W + 185728;   // 5120  -> 190848
  float* upart  = W + 190848;   // 8192  -> 199040
  float* w1part = W + 199040;   // 9728  -> 208768 floats (835072 B)
  bf16_t* M16 = (bf16_t*)((char*)d_ws + 851968);   // 128 KB
  bf16_t* fB  = (bf16_t*)((char*)d_ws + 983040);   // 512 KB (m-major raw)
  bf16_t* fBT = (bf16_t*)((char*)d_ws + 1507328);  // 512 KB (q-major)
  bf16_t* xT  = (bf16_t*)((char*)d_ws + 2031616);  // 8 MB  (x transposed bf16)
  // total ws usage ~9.95 MB

  k_front<<<1789, 256, 0, stream>>>(final_w, gw_w, emb, wq, bq, wk, bk, wv, bv, x,
                                    phi_w, phi_b, s2l_w, gc1_w, wo, bo,
                                    M16, qkv, fB, fBT, s_raw, xsump, csum,
                                    fmaxp, cmaxp, xT, E1, WG1, bg1);
  k_mid1<<<18, 512, 0, stream>>>(adj, qkv, E1, glob_w, xsump, s_raw,
                                 fmaxp, cmaxp,
                                 n1, adjn, rsA, AE1, dgd, mcol, fmaxb, cmaxb);
  k_w1<<<38, 256, 0, stream>>>(n1, WG1, w1part);
  k_gu<<<32, 256, 0, stream>>>(w1part, bg1, AE1, rsA, adjn, gc2_w, final_w, upart);
  k_main<<<dim3(32, 16), 256, 0, stream>>>(x, fB, fBT, xT, M16, fmaxb, mcol, upart,
                                           dgd, csum, cmaxb, out);
}